// Round 4
// baseline (2864.675 us; speedup 1.0000x reference)
//
#include <hip/hip_runtime.h>
#include <math.h>

#define NSLOPE 0.01f
#define BGRAPH 128
#define PPARTS 8
#define GTILE 128
#define BK 32
#define PNB 64        // partition blocks (must match across hist/offs/partition)
#define MAXBUK 2048   // >= (2N+127)/128

__device__ __forceinline__ float lrelu(float v) { return v >= 0.f ? v : NSLOPE * v; }

// ---------- degree count / scans over combined node space [0, 2N) ----------

__global__ void cnt_zero_kernel(int* __restrict__ cnt, int n) {
  int v = blockIdx.x * blockDim.x + threadIdx.x;
  if (v < n) cnt[v] = 0;
}

__global__ void count_kernel(const int* __restrict__ dst1, const int* __restrict__ dst2,
                             int* __restrict__ cnt, int ne, int off) {
  int e = blockIdx.x * blockDim.x + threadIdx.x;
  if (e < ne) atomicAdd(&cnt[dst1[e]], 1);
  else if (e < 2 * ne) atomicAdd(&cnt[dst2[e - ne] + off], 1);
}

__global__ void part_sum_kernel(const int* __restrict__ cnt, int* __restrict__ part, int n) {
  __shared__ int s[256];
  int t = threadIdx.x;
  int v = blockIdx.x * 256 + t;
  s[t] = (v < n) ? cnt[v] : 0;
  __syncthreads();
  for (int off = 128; off > 0; off >>= 1) {
    if (t < off) s[t] += s[t + off];
    __syncthreads();
  }
  if (t == 0) part[blockIdx.x] = s[0];
}

__global__ void part_scan_kernel(int* __restrict__ part, int nb) {
  __shared__ int s[1024];
  int t = threadIdx.x;
  int v = (t < nb) ? part[t] : 0;
  s[t] = v;
  __syncthreads();
  for (int off = 1; off < 1024; off <<= 1) {
    int a = (t >= off) ? s[t - off] : 0;
    __syncthreads();
    s[t] += a;
    __syncthreads();
  }
  if (t < nb) part[t] = s[t] - v;  // exclusive
}

__global__ void rowptr_kernel(const int* __restrict__ cnt, const int* __restrict__ part,
                              int* __restrict__ rowptr, float* __restrict__ dinv,
                              int n, int ne) {
  __shared__ int s[256];
  int t = threadIdx.x;
  int v = blockIdx.x * 256 + t;
  int c = (v < n) ? cnt[v] : 0;
  s[t] = c;
  __syncthreads();
  for (int off = 1; off < 256; off <<= 1) {
    int a = (t >= off) ? s[t - off] : 0;
    __syncthreads();
    s[t] += a;
    __syncthreads();
  }
  int excl = s[t] - c + part[blockIdx.x];
  if (v < n) {
    rowptr[v] = excl;
    dinv[v] = rsqrtf((float)(c + 1));
  }
  if (v == n - 1) rowptr[n] = ne;
}

// ---------- hierarchical edge partition into 128-node buckets ----------

__global__ __launch_bounds__(1024) void hist_kernel(
    const int* __restrict__ dst1, const int* __restrict__ dst2,
    int* __restrict__ hist, int ne, int off, int nbuk) {
  __shared__ int h[MAXBUK];
  for (int i = threadIdx.x; i < nbuk; i += 1024) h[i] = 0;
  __syncthreads();
  int total = 2 * ne;
  int chunk = (total + gridDim.x - 1) / gridDim.x;
  int a = blockIdx.x * chunk;
  int b = min(total, a + chunk);
  for (int e = a + threadIdx.x; e < b; e += 1024) {
    int d = (e < ne) ? dst1[e] : dst2[e - ne] + off;
    atomicAdd(&h[d >> 7], 1);
  }
  __syncthreads();
  for (int i = threadIdx.x; i < nbuk; i += 1024)
    hist[blockIdx.x * nbuk + i] = h[i];
}

// offs[blk][b] = rowptr[b*128] + prefix over blocks of hist[.][b]; one wave per bucket
__global__ void offs_kernel(const int* __restrict__ hist, const int* __restrict__ rowptr,
                            int* __restrict__ offs, int nbuk) {
  int b = blockIdx.x;
  int t = threadIdx.x;  // 0..63, one wave
  int v = hist[t * nbuk + b];
  int sum = v;
  for (int o = 1; o < 64; o <<= 1) {
    int u = __shfl_up(sum, o);
    if (t >= o) sum += u;
  }
  offs[t * nbuk + b] = rowptr[b * 128] + (sum - v);
}

__global__ __launch_bounds__(1024) void partition_kernel(
    const int* __restrict__ s1, const int* __restrict__ d1,
    const int* __restrict__ s2, const int* __restrict__ d2,
    const int* __restrict__ offs, int* __restrict__ ebuf,
    int ne, int off, int nbuk) {
  __shared__ int cur[MAXBUK];
  for (int i = threadIdx.x; i < nbuk; i += 1024)
    cur[i] = offs[blockIdx.x * nbuk + i];
  __syncthreads();
  int total = 2 * ne;
  int chunk = (total + gridDim.x - 1) / gridDim.x;
  int a = blockIdx.x * chunk;
  int b = min(total, a + chunk);
  for (int e = a + threadIdx.x; e < b; e += 1024) {
    int s, d;
    if (e < ne) { s = s1[e]; d = d1[e]; }
    else { s = s2[e - ne] + off; d = d2[e - ne] + off; }
    int p = atomicAdd(&cur[d >> 7], 1);
    ebuf[p] = (s << 7) | (d & 127);  // s < 2^18 -> fits 25 bits
  }
}

// ---------- LDS-accumulating gather: one block per 128-node bucket ----------
// agg[v] = dinv[v] * (dinv[v]*x[v] + sum_{s in N(v)} dinv[s]*x[s])
__global__ __launch_bounds__(512) void gather_lds_kernel(
    const float* __restrict__ x1, const float* __restrict__ x2,
    const int* __restrict__ ebuf, const int* __restrict__ rowptr,
    const float* __restrict__ dinv, float* __restrict__ agg,
    int n1, int ntot) {
  __shared__ float acc[128 * 128];  // exactly 64 KB
  int t = threadIdx.x;
  int v0 = blockIdx.x * 128;
  for (int idx = t; idx < 128 * 128; idx += 512) {
    int r = idx >> 7, c = idx & 127;
    int v = v0 + r;
    float val = 0.f;
    if (v < ntot) {
      float dv = dinv[v];
      float xv = (v < n1) ? x1[(size_t)v * 128 + c] : x2[(size_t)(v - n1) * 128 + c];
      val = dv * xv;
    }
    acc[idx] = val;
  }
  __syncthreads();
  int e0 = rowptr[v0];
  int vend = v0 + 128; if (vend > ntot) vend = ntot;
  int e1 = rowptr[vend];
  int group = t >> 5, lane = t & 31;
  for (int i = e0 + group; i < e1; i += 16) {
    int pack = ebuf[i];
    int s = pack >> 7;
    int r = pack & 127;
    float ds = dinv[s];
    const float* px = (s < n1) ? (x1 + (size_t)s * 128) : (x2 + (size_t)(s - n1) * 128);
#pragma unroll
    for (int j = 0; j < 4; j++) {
      // addr = r*128 + j*32 + lane -> bank = lane: conflict-free (2 edges/wave = 2-way, free)
      atomicAdd(&acc[r * 128 + j * 32 + lane], ds * px[j * 32 + lane]);
    }
  }
  __syncthreads();
  for (int idx = t; idx < 128 * 128; idx += 512) {
    int r = idx >> 7, c = idx & 127;
    int v = v0 + r;
    if (v < ntot) agg[(size_t)v * 128 + c] = dinv[v] * acc[idx];
  }
}

// ---------- register-tiled GEMM: C = lrelu(A@W + b), in place on agg ----------
__global__ __launch_bounds__(256, 3) void gemm_tiled_kernel(
    const float* A, float* C,
    const float* __restrict__ W1, const float* __restrict__ b1,
    const float* __restrict__ W2, const float* __restrict__ b2,
    int N1, int Ntot, int nbA) {
  __shared__ float xs[BK * 132];
  __shared__ float wsm[BK * 128];
  int b = blockIdx.x;
  int half = (b >= nbA) ? 1 : 0;
  const float* W = half ? W2 : W1;
  const float* bias = half ? b2 : b1;
  int base = half ? (N1 + (b - nbA) * GTILE) : b * GTILE;
  int rmax = half ? Ntot : N1;
  int t = threadIdx.x;
  int tr = t & 15, tc = t >> 4;
  int r0 = tr * 8, c0 = tc * 8;

  float acc[8][8];
#pragma unroll
  for (int i = 0; i < 8; i++)
#pragma unroll
    for (int j = 0; j < 8; j++) acc[i][j] = 0.f;

  for (int kc = 0; kc < 128; kc += BK) {
#pragma unroll
    for (int i = 0; i < 4; i++) {
      int idx = t + i * 256;
      int row = idx >> 3;
      int kq = idx & 7;
      int gr = base + row;
      float4 av = make_float4(0.f, 0.f, 0.f, 0.f);
      if (gr < rmax) av = ((const float4*)(A + (size_t)gr * 128 + kc))[kq];
      xs[(kq * 4 + 0) * 132 + row] = av.x;
      xs[(kq * 4 + 1) * 132 + row] = av.y;
      xs[(kq * 4 + 2) * 132 + row] = av.z;
      xs[(kq * 4 + 3) * 132 + row] = av.w;
    }
#pragma unroll
    for (int i = 0; i < 4; i++) {
      int idx = t + i * 256;
      int k = idx >> 5, c4 = idx & 31;
      ((float4*)wsm)[k * 32 + c4] = ((const float4*)(W + (size_t)(kc + k) * 128))[c4];
    }
    __syncthreads();
#pragma unroll 8
    for (int k = 0; k < BK; k++) {
      float4 a0 = *(const float4*)(xs + k * 132 + r0);
      float4 a1 = *(const float4*)(xs + k * 132 + r0 + 4);
      float4 w0 = *(const float4*)(wsm + k * 128 + c0);
      float4 w1 = *(const float4*)(wsm + k * 128 + c0 + 4);
      float av[8] = {a0.x, a0.y, a0.z, a0.w, a1.x, a1.y, a1.z, a1.w};
      float wv[8] = {w0.x, w0.y, w0.z, w0.w, w1.x, w1.y, w1.z, w1.w};
#pragma unroll
      for (int i = 0; i < 8; i++)
#pragma unroll
        for (int j = 0; j < 8; j++) acc[i][j] = fmaf(av[i], wv[j], acc[i][j]);
    }
    __syncthreads();
  }

  float bv[8];
#pragma unroll
  for (int j = 0; j < 8; j++) bv[j] = bias[c0 + j];
#pragma unroll
  for (int i = 0; i < 8; i++) {
    int gr = base + r0 + i;
    if (gr < rmax) {
      float4 o0, o1;
      o0.x = lrelu(acc[i][0] + bv[0]); o0.y = lrelu(acc[i][1] + bv[1]);
      o0.z = lrelu(acc[i][2] + bv[2]); o0.w = lrelu(acc[i][3] + bv[3]);
      o1.x = lrelu(acc[i][4] + bv[4]); o1.y = lrelu(acc[i][5] + bv[5]);
      o1.z = lrelu(acc[i][6] + bv[6]); o1.w = lrelu(acc[i][7] + bv[7]);
      *(float4*)(C + (size_t)gr * 128 + c0) = o0;
      *(float4*)(C + (size_t)gr * 128 + c0 + 4) = o1;
    }
  }
}

// ---------- pooling over 256 combined graphs ----------

__global__ void bounds_kernel(const int* __restrict__ b1, const int* __restrict__ b2,
                              int* __restrict__ start, int n, int nb) {
  int b = blockIdx.x * blockDim.x + threadIdx.x;
  if (b > 2 * nb) return;
  const int* arr;
  int tgt, off;
  if (b < nb) { arr = b1; tgt = b; off = 0; }
  else { arr = b2; tgt = b - nb; off = n; }
  int lo = 0, hi = n;
  while (lo < hi) {
    int mid = (lo + hi) >> 1;
    if (arr[mid] < tgt) lo = mid + 1; else hi = mid;
  }
  start[b] = off + lo;
}

__global__ void pool_part_kernel(const float* __restrict__ h, const int* __restrict__ start,
                                 float* __restrict__ part) {
  int b = blockIdx.x / PPARTS, p = blockIdx.x % PPARTS;
  int t = threadIdx.x;
  int s0 = start[b], s1 = start[b + 1];
  int cnt = s1 - s0;
  int per = (cnt + PPARTS - 1) / PPARTS;
  int v0 = s0 + p * per;
  int v1 = min(s1, v0 + per);
  float m = -3.4e38f;
  for (int v = v0; v < v1; v++) m = fmaxf(m, h[(size_t)v * 128 + t]);
  part[(size_t)blockIdx.x * 128 + t] = m;
}

__global__ void pool_combine_kernel(const float* __restrict__ part, float* __restrict__ g) {
  int b = blockIdx.x, t = threadIdx.x;
  float m = -3.4e38f;
#pragma unroll
  for (int p = 0; p < PPARTS; p++) m = fmaxf(m, part[((size_t)b * PPARTS + p) * 128 + t]);
  g[(size_t)b * 128 + t] = m;
}

// ---------- fused head ----------

__global__ __launch_bounds__(256) void head_kernel(
    const float* __restrict__ g1, const float* __restrict__ g2,
    const float* __restrict__ fcp1W, const float* __restrict__ fcp1b,
    const float* __restrict__ fcp2W, const float* __restrict__ fcp2b,
    const float* __restrict__ fc1W, const float* __restrict__ fc1b,
    const float* __restrict__ fc2W, const float* __restrict__ fc2b,
    const float* __restrict__ outW, const float* __restrict__ outb,
    float* __restrict__ out) {
  __shared__ float grow[256];
  __shared__ float c[256];
  __shared__ float h1[256];
  __shared__ float h2[64];
  int b = blockIdx.x, t = threadIdx.x;
  grow[t] = (t < 128) ? g1[b * 128 + t] : g2[b * 128 + (t - 128)];
  __syncthreads();
  {
    float acc;
    if (t < 128) {
      acc = fcp1b[t];
      for (int k = 0; k < 128; k++) acc = fmaf(grow[k], fcp1W[k * 128 + t], acc);
    } else {
      int tc = t - 128;
      acc = fcp2b[tc];
      for (int k = 0; k < 128; k++) acc = fmaf(grow[128 + k], fcp2W[k * 128 + tc], acc);
    }
    c[t] = lrelu(acc);
  }
  __syncthreads();
  {
    float acc = fc1b[t];
    for (int k = 0; k < 256; k++) acc = fmaf(c[k], fc1W[k * 256 + t], acc);
    h1[t] = lrelu(acc);
  }
  __syncthreads();
  if (t < 64) {
    float acc = fc2b[t];
    for (int k = 0; k < 256; k++) acc = fmaf(h1[k], fc2W[k * 64 + t], acc);
    h2[t] = lrelu(acc);
  }
  __syncthreads();
  if (t < 64) {
    float v = h2[t] * outW[t];
    for (int off = 32; off > 0; off >>= 1) v += __shfl_down(v, off);
    if (t == 0) out[b] = 1.f / (1.f + expf(-(v + outb[0])));
  }
}

extern "C" void kernel_launch(void* const* d_in, const int* in_sizes, int n_in,
                              void* d_out, int out_size, void* d_ws, size_t ws_size,
                              hipStream_t stream) {
  const float* x1 = (const float*)d_in[0];
  const float* x2 = (const float*)d_in[1];
  const int* ei1 = (const int*)d_in[2];
  const int* ei2 = (const int*)d_in[3];
  const int* batch1 = (const int*)d_in[4];
  const int* batch2 = (const int*)d_in[5];
  const float* conv1W = (const float*)d_in[6];
  const float* conv1b = (const float*)d_in[7];
  const float* conv2W = (const float*)d_in[8];
  const float* conv2b = (const float*)d_in[9];
  const float* fcp1W = (const float*)d_in[10];
  const float* fcp1b = (const float*)d_in[11];
  const float* fcp2W = (const float*)d_in[12];
  const float* fcp2b = (const float*)d_in[13];
  const float* fc1W = (const float*)d_in[14];
  const float* fc1b = (const float*)d_in[15];
  const float* fc2W = (const float*)d_in[16];
  const float* fc2b = (const float*)d_in[17];
  const float* outW = (const float*)d_in[18];
  const float* outb = (const float*)d_in[19];

  int N = in_sizes[0] / 128;
  int E = in_sizes[2] / 2;
  int NT = 2 * N;
  int nblk2 = (NT + 255) / 256;
  int NBUK = (NT + 127) / 128;

  char* ws = (char*)d_ws;
  size_t off = 0;
  auto alloc = [&](size_t bytes) -> void* {
    void* p = ws + off;
    off += (bytes + 511) & ~(size_t)511;
    return p;
  };
  float* agg = (float*)alloc((size_t)NT * 128 * 4);      // 102.4 MB
  int* ebuf = (int*)alloc((size_t)2 * E * 4);            // 12.8 MB
  int* cnt = (int*)alloc((size_t)NT * 4);
  int* rowptr = (int*)alloc((size_t)(NT + 1) * 4);
  int* part_i = (int*)alloc((size_t)1024 * 4);
  float* dinv = (float*)alloc((size_t)NT * 4);
  int* hist = (int*)alloc((size_t)PNB * NBUK * 4);
  int* offs = (int*)alloc((size_t)PNB * NBUK * 4);
  float* part = (float*)alloc((size_t)2 * BGRAPH * PPARTS * 128 * 4);
  int* start = (int*)alloc((size_t)(2 * BGRAPH + 1) * 4);
  float* g = (float*)alloc((size_t)2 * BGRAPH * 128 * 4);
  (void)ws_size; (void)n_in; (void)out_size;

  const int* src1 = ei1, *dst1 = ei1 + E;
  const int* src2 = ei2, *dst2 = ei2 + E;

  cnt_zero_kernel<<<nblk2, 256, 0, stream>>>(cnt, NT);
  count_kernel<<<(2 * E + 255) / 256, 256, 0, stream>>>(dst1, dst2, cnt, E, N);
  part_sum_kernel<<<nblk2, 256, 0, stream>>>(cnt, part_i, NT);
  part_scan_kernel<<<1, 1024, 0, stream>>>(part_i, nblk2);
  rowptr_kernel<<<nblk2, 256, 0, stream>>>(cnt, part_i, rowptr, dinv, NT, 2 * E);
  hist_kernel<<<PNB, 1024, 0, stream>>>(dst1, dst2, hist, E, N, NBUK);
  offs_kernel<<<NBUK, 64, 0, stream>>>(hist, rowptr, offs, NBUK);
  partition_kernel<<<PNB, 1024, 0, stream>>>(src1, dst1, src2, dst2, offs, ebuf, E, N, NBUK);
  gather_lds_kernel<<<NBUK, 512, 0, stream>>>(x1, x2, ebuf, rowptr, dinv, agg, N, NT);
  int nbA = (N + GTILE - 1) / GTILE;
  gemm_tiled_kernel<<<2 * nbA, 256, 0, stream>>>(agg, agg, conv1W, conv1b,
                                                 conv2W, conv2b, N, NT, nbA);
  bounds_kernel<<<2, 256, 0, stream>>>(batch1, batch2, start, N, BGRAPH);
  pool_part_kernel<<<2 * BGRAPH * PPARTS, 128, 0, stream>>>(agg, start, part);
  pool_combine_kernel<<<2 * BGRAPH, 128, 0, stream>>>(part, g);

  head_kernel<<<BGRAPH, 256, 0, stream>>>(g, g + (size_t)BGRAPH * 128,
                                          fcp1W, fcp1b, fcp2W, fcp2b,
                                          fc1W, fc1b, fc2W, fc2b, outW, outb,
                                          (float*)d_out);
}

// Round 5
// 781.381 us; speedup vs baseline: 3.6662x; 3.6662x over previous
//
#include <hip/hip_runtime.h>
#include <math.h>

#define NSLOPE 0.01f
#define BGRAPH 128
#define PPARTS 8
#define GTILE 128
#define BK 32
#define PNB 64        // partition blocks
#define MAXBUK 2048   // >= (2N+127)/128
#define SCAP 4608     // bucket sort capacity (mean 2048, sigma ~45)

__device__ __forceinline__ float lrelu(float v) { return v >= 0.f ? v : NSLOPE * v; }

// ---------- degree count / scans over combined node space [0, 2N) ----------

__global__ void cnt_zero_kernel(int* __restrict__ cnt, int n) {
  int v = blockIdx.x * blockDim.x + threadIdx.x;
  if (v < n) cnt[v] = 0;
}

__global__ void count_kernel(const int* __restrict__ dst1, const int* __restrict__ dst2,
                             int* __restrict__ cnt, int ne, int off) {
  int e = blockIdx.x * blockDim.x + threadIdx.x;
  if (e < ne) atomicAdd(&cnt[dst1[e]], 1);
  else if (e < 2 * ne) atomicAdd(&cnt[dst2[e - ne] + off], 1);
}

__global__ void part_sum_kernel(const int* __restrict__ cnt, int* __restrict__ part, int n) {
  __shared__ int s[256];
  int t = threadIdx.x;
  int v = blockIdx.x * 256 + t;
  s[t] = (v < n) ? cnt[v] : 0;
  __syncthreads();
  for (int off = 128; off > 0; off >>= 1) {
    if (t < off) s[t] += s[t + off];
    __syncthreads();
  }
  if (t == 0) part[blockIdx.x] = s[0];
}

__global__ void part_scan_kernel(int* __restrict__ part, int nb) {
  __shared__ int s[1024];
  int t = threadIdx.x;
  int v = (t < nb) ? part[t] : 0;
  s[t] = v;
  __syncthreads();
  for (int off = 1; off < 1024; off <<= 1) {
    int a = (t >= off) ? s[t - off] : 0;
    __syncthreads();
    s[t] += a;
    __syncthreads();
  }
  if (t < nb) part[t] = s[t] - v;  // exclusive
}

__global__ void rowptr_kernel(const int* __restrict__ cnt, const int* __restrict__ part,
                              int* __restrict__ rowptr, float* __restrict__ dinv,
                              int n, int ne) {
  __shared__ int s[256];
  int t = threadIdx.x;
  int v = blockIdx.x * 256 + t;
  int c = (v < n) ? cnt[v] : 0;
  s[t] = c;
  __syncthreads();
  for (int off = 1; off < 256; off <<= 1) {
    int a = (t >= off) ? s[t - off] : 0;
    __syncthreads();
    s[t] += a;
    __syncthreads();
  }
  int excl = s[t] - c + part[blockIdx.x];
  if (v < n) {
    rowptr[v] = excl;
    dinv[v] = rsqrtf((float)(c + 1));
  }
  if (v == n - 1) rowptr[n] = ne;
}

// ---------- hierarchical edge partition into 128-node buckets ----------

__global__ __launch_bounds__(1024) void hist_kernel(
    const int* __restrict__ dst1, const int* __restrict__ dst2,
    int* __restrict__ hist, int ne, int off, int nbuk) {
  __shared__ int h[MAXBUK];
  for (int i = threadIdx.x; i < nbuk; i += 1024) h[i] = 0;
  __syncthreads();
  int total = 2 * ne;
  int chunk = (total + gridDim.x - 1) / gridDim.x;
  int a = blockIdx.x * chunk;
  int b = min(total, a + chunk);
  for (int e = a + threadIdx.x; e < b; e += 1024) {
    int d = (e < ne) ? dst1[e] : dst2[e - ne] + off;
    atomicAdd(&h[d >> 7], 1);
  }
  __syncthreads();
  for (int i = threadIdx.x; i < nbuk; i += 1024)
    hist[blockIdx.x * nbuk + i] = h[i];
}

// offs[blk][b] = rowptr[b*128] + prefix over blocks of hist[.][b]; one wave per bucket
__global__ void offs_kernel(const int* __restrict__ hist, const int* __restrict__ rowptr,
                            int* __restrict__ offs, int nbuk) {
  int b = blockIdx.x;
  int t = threadIdx.x;  // 0..63, one wave
  int v = hist[t * nbuk + b];
  int sum = v;
  for (int o = 1; o < 64; o <<= 1) {
    int u = __shfl_up(sum, o);
    if (t >= o) sum += u;
  }
  offs[t * nbuk + b] = rowptr[b * 128] + (sum - v);
}

__global__ __launch_bounds__(1024) void partition_kernel(
    const int* __restrict__ s1, const int* __restrict__ d1,
    const int* __restrict__ s2, const int* __restrict__ d2,
    const int* __restrict__ offs, int* __restrict__ ebuf,
    int ne, int off, int nbuk) {
  __shared__ int cur[MAXBUK];
  for (int i = threadIdx.x; i < nbuk; i += 1024)
    cur[i] = offs[blockIdx.x * nbuk + i];
  __syncthreads();
  int total = 2 * ne;
  int chunk = (total + gridDim.x - 1) / gridDim.x;
  int a = blockIdx.x * chunk;
  int b = min(total, a + chunk);
  for (int e = a + threadIdx.x; e < b; e += 1024) {
    int s, d;
    if (e < ne) { s = s1[e]; d = d1[e]; }
    else { s = s2[e - ne] + off; d = d2[e - ne] + off; }
    int p = atomicAdd(&cur[d >> 7], 1);
    ebuf[p] = (s << 7) | (d & 127);  // s < 2^18 -> fits 25 bits
  }
}

// counting-sort each bucket's edges by dst in LDS; ebuf becomes per-node CSR of src
__global__ __launch_bounds__(256) void bucket_sort_kernel(
    int* __restrict__ ebuf, const int* __restrict__ rowptr, int ntot) {
  __shared__ int buf[SCAP];
  __shared__ int outv[SCAP];
  __shared__ int cur[128];
  int b = blockIdx.x, t = threadIdx.x;
  int v0 = b * 128;
  int vend = min(v0 + 128, ntot);
  int e0 = rowptr[v0], e1 = rowptr[vend];
  int cnt = e1 - e0;
  for (int r = t; r < 128; r += 256) {
    int v = v0 + r;
    cur[r] = (v < ntot) ? (rowptr[v] - e0) : 0;
  }
  for (int i = t; i < cnt; i += 256) buf[i] = ebuf[e0 + i];
  __syncthreads();
  for (int i = t; i < cnt; i += 256) {
    int pack = buf[i];
    int pos = atomicAdd(&cur[pack & 127], 1);
    outv[pos] = pack >> 7;
  }
  __syncthreads();
  for (int i = t; i < cnt; i += 256) ebuf[e0 + i] = outv[i];
}

// agg[v] = dinv[v] * (dinv[v]*x[v] + sum_{s in N(v)} dinv[s]*x[s])
// 32 lanes per node, float4 per lane; batch-of-32 csr loads + shuffle broadcast.
__global__ void gather_kernel(const float* __restrict__ x1, const float* __restrict__ x2,
                              const int* __restrict__ csr, const int* __restrict__ rowptr,
                              const float* __restrict__ dinv, float* __restrict__ agg,
                              int n1, int ntot) {
  int tid = blockIdx.x * blockDim.x + threadIdx.x;
  int v = tid >> 5, l = tid & 31;
  if (v >= ntot) return;
  float dv = dinv[v];
  const float* xself = (v < n1) ? (x1 + (size_t)v * 128) : (x2 + (size_t)(v - n1) * 128);
  float4 xv0 = ((const float4*)xself)[l];
  float4 acc0, acc1;
  acc0.x = dv * xv0.x; acc0.y = dv * xv0.y; acc0.z = dv * xv0.z; acc0.w = dv * xv0.w;
  acc1.x = 0.f; acc1.y = 0.f; acc1.z = 0.f; acc1.w = 0.f;
  int rs = rowptr[v], re = rowptr[v + 1];
  for (int base = rs; base < re; base += 32) {
    int idx = base + l;
    int sown = (idx < re) ? csr[idx] : 0;
    float down = (idx < re) ? dinv[sown] : 0.f;
    int m = min(32, re - base);
    for (int j = 0; j < m; j++) {
      int s = __shfl(sown, j, 32);
      float ds = __shfl(down, j, 32);
      const float* px = (s < n1) ? (x1 + (size_t)s * 128) : (x2 + (size_t)(s - n1) * 128);
      float4 xv = ((const float4*)px)[l];
      if (j & 1) {
        acc1.x = fmaf(ds, xv.x, acc1.x); acc1.y = fmaf(ds, xv.y, acc1.y);
        acc1.z = fmaf(ds, xv.z, acc1.z); acc1.w = fmaf(ds, xv.w, acc1.w);
      } else {
        acc0.x = fmaf(ds, xv.x, acc0.x); acc0.y = fmaf(ds, xv.y, acc0.y);
        acc0.z = fmaf(ds, xv.z, acc0.z); acc0.w = fmaf(ds, xv.w, acc0.w);
      }
    }
  }
  float4 o;
  o.x = dv * (acc0.x + acc1.x); o.y = dv * (acc0.y + acc1.y);
  o.z = dv * (acc0.z + acc1.z); o.w = dv * (acc0.w + acc1.w);
  ((float4*)agg)[(size_t)v * 32 + l] = o;
}

// ---------- register-tiled GEMM: C = lrelu(A@W + b), in place on agg ----------
__global__ __launch_bounds__(256, 3) void gemm_tiled_kernel(
    const float* A, float* C,
    const float* __restrict__ W1, const float* __restrict__ b1,
    const float* __restrict__ W2, const float* __restrict__ b2,
    int N1, int Ntot, int nbA) {
  __shared__ float xs[BK * 132];
  __shared__ float wsm[BK * 128];
  int b = blockIdx.x;
  int half = (b >= nbA) ? 1 : 0;
  const float* W = half ? W2 : W1;
  const float* bias = half ? b2 : b1;
  int base = half ? (N1 + (b - nbA) * GTILE) : b * GTILE;
  int rmax = half ? Ntot : N1;
  int t = threadIdx.x;
  int tr = t & 15, tc = t >> 4;
  int r0 = tr * 8, c0 = tc * 8;

  float acc[8][8];
#pragma unroll
  for (int i = 0; i < 8; i++)
#pragma unroll
    for (int j = 0; j < 8; j++) acc[i][j] = 0.f;

  for (int kc = 0; kc < 128; kc += BK) {
#pragma unroll
    for (int i = 0; i < 4; i++) {
      int idx = t + i * 256;
      int row = idx >> 3;
      int kq = idx & 7;
      int gr = base + row;
      float4 av = make_float4(0.f, 0.f, 0.f, 0.f);
      if (gr < rmax) av = ((const float4*)(A + (size_t)gr * 128 + kc))[kq];
      xs[(kq * 4 + 0) * 132 + row] = av.x;
      xs[(kq * 4 + 1) * 132 + row] = av.y;
      xs[(kq * 4 + 2) * 132 + row] = av.z;
      xs[(kq * 4 + 3) * 132 + row] = av.w;
    }
#pragma unroll
    for (int i = 0; i < 4; i++) {
      int idx = t + i * 256;
      int k = idx >> 5, c4 = idx & 31;
      ((float4*)wsm)[k * 32 + c4] = ((const float4*)(W + (size_t)(kc + k) * 128))[c4];
    }
    __syncthreads();
#pragma unroll 8
    for (int k = 0; k < BK; k++) {
      float4 a0 = *(const float4*)(xs + k * 132 + r0);
      float4 a1 = *(const float4*)(xs + k * 132 + r0 + 4);
      float4 w0 = *(const float4*)(wsm + k * 128 + c0);
      float4 w1 = *(const float4*)(wsm + k * 128 + c0 + 4);
      float av[8] = {a0.x, a0.y, a0.z, a0.w, a1.x, a1.y, a1.z, a1.w};
      float wv[8] = {w0.x, w0.y, w0.z, w0.w, w1.x, w1.y, w1.z, w1.w};
#pragma unroll
      for (int i = 0; i < 8; i++)
#pragma unroll
        for (int j = 0; j < 8; j++) acc[i][j] = fmaf(av[i], wv[j], acc[i][j]);
    }
    __syncthreads();
  }

  float bv[8];
#pragma unroll
  for (int j = 0; j < 8; j++) bv[j] = bias[c0 + j];
#pragma unroll
  for (int i = 0; i < 8; i++) {
    int gr = base + r0 + i;
    if (gr < rmax) {
      float4 o0, o1;
      o0.x = lrelu(acc[i][0] + bv[0]); o0.y = lrelu(acc[i][1] + bv[1]);
      o0.z = lrelu(acc[i][2] + bv[2]); o0.w = lrelu(acc[i][3] + bv[3]);
      o1.x = lrelu(acc[i][4] + bv[4]); o1.y = lrelu(acc[i][5] + bv[5]);
      o1.z = lrelu(acc[i][6] + bv[6]); o1.w = lrelu(acc[i][7] + bv[7]);
      *(float4*)(C + (size_t)gr * 128 + c0) = o0;
      *(float4*)(C + (size_t)gr * 128 + c0 + 4) = o1;
    }
  }
}

// ---------- pooling over 256 combined graphs ----------

__global__ void bounds_kernel(const int* __restrict__ b1, const int* __restrict__ b2,
                              int* __restrict__ start, int n, int nb) {
  int b = blockIdx.x * blockDim.x + threadIdx.x;
  if (b > 2 * nb) return;
  const int* arr;
  int tgt, off;
  if (b < nb) { arr = b1; tgt = b; off = 0; }
  else { arr = b2; tgt = b - nb; off = n; }
  int lo = 0, hi = n;
  while (lo < hi) {
    int mid = (lo + hi) >> 1;
    if (arr[mid] < tgt) lo = mid + 1; else hi = mid;
  }
  start[b] = off + lo;
}

__global__ void pool_part_kernel(const float* __restrict__ h, const int* __restrict__ start,
                                 float* __restrict__ part) {
  int b = blockIdx.x / PPARTS, p = blockIdx.x % PPARTS;
  int t = threadIdx.x;
  int s0 = start[b], s1 = start[b + 1];
  int cnt = s1 - s0;
  int per = (cnt + PPARTS - 1) / PPARTS;
  int v0 = s0 + p * per;
  int v1 = min(s1, v0 + per);
  float m = -3.4e38f;
  for (int v = v0; v < v1; v++) m = fmaxf(m, h[(size_t)v * 128 + t]);
  part[(size_t)blockIdx.x * 128 + t] = m;
}

__global__ void pool_combine_kernel(const float* __restrict__ part, float* __restrict__ g) {
  int b = blockIdx.x, t = threadIdx.x;
  float m = -3.4e38f;
#pragma unroll
  for (int p = 0; p < PPARTS; p++) m = fmaxf(m, part[((size_t)b * PPARTS + p) * 128 + t]);
  g[(size_t)b * 128 + t] = m;
}

// ---------- fused head ----------

__global__ __launch_bounds__(256) void head_kernel(
    const float* __restrict__ g1, const float* __restrict__ g2,
    const float* __restrict__ fcp1W, const float* __restrict__ fcp1b,
    const float* __restrict__ fcp2W, const float* __restrict__ fcp2b,
    const float* __restrict__ fc1W, const float* __restrict__ fc1b,
    const float* __restrict__ fc2W, const float* __restrict__ fc2b,
    const float* __restrict__ outW, const float* __restrict__ outb,
    float* __restrict__ out) {
  __shared__ float grow[256];
  __shared__ float c[256];
  __shared__ float h1[256];
  __shared__ float h2[64];
  int b = blockIdx.x, t = threadIdx.x;
  grow[t] = (t < 128) ? g1[b * 128 + t] : g2[b * 128 + (t - 128)];
  __syncthreads();
  {
    float acc;
    if (t < 128) {
      acc = fcp1b[t];
      for (int k = 0; k < 128; k++) acc = fmaf(grow[k], fcp1W[k * 128 + t], acc);
    } else {
      int tc = t - 128;
      acc = fcp2b[tc];
      for (int k = 0; k < 128; k++) acc = fmaf(grow[128 + k], fcp2W[k * 128 + tc], acc);
    }
    c[t] = lrelu(acc);
  }
  __syncthreads();
  {
    float acc = fc1b[t];
    for (int k = 0; k < 256; k++) acc = fmaf(c[k], fc1W[k * 256 + t], acc);
    h1[t] = lrelu(acc);
  }
  __syncthreads();
  if (t < 64) {
    float acc = fc2b[t];
    for (int k = 0; k < 256; k++) acc = fmaf(h1[k], fc2W[k * 64 + t], acc);
    h2[t] = lrelu(acc);
  }
  __syncthreads();
  if (t < 64) {
    float v = h2[t] * outW[t];
    for (int off = 32; off > 0; off >>= 1) v += __shfl_down(v, off);
    if (t == 0) out[b] = 1.f / (1.f + expf(-(v + outb[0])));
  }
}

extern "C" void kernel_launch(void* const* d_in, const int* in_sizes, int n_in,
                              void* d_out, int out_size, void* d_ws, size_t ws_size,
                              hipStream_t stream) {
  const float* x1 = (const float*)d_in[0];
  const float* x2 = (const float*)d_in[1];
  const int* ei1 = (const int*)d_in[2];
  const int* ei2 = (const int*)d_in[3];
  const int* batch1 = (const int*)d_in[4];
  const int* batch2 = (const int*)d_in[5];
  const float* conv1W = (const float*)d_in[6];
  const float* conv1b = (const float*)d_in[7];
  const float* conv2W = (const float*)d_in[8];
  const float* conv2b = (const float*)d_in[9];
  const float* fcp1W = (const float*)d_in[10];
  const float* fcp1b = (const float*)d_in[11];
  const float* fcp2W = (const float*)d_in[12];
  const float* fcp2b = (const float*)d_in[13];
  const float* fc1W = (const float*)d_in[14];
  const float* fc1b = (const float*)d_in[15];
  const float* fc2W = (const float*)d_in[16];
  const float* fc2b = (const float*)d_in[17];
  const float* outW = (const float*)d_in[18];
  const float* outb = (const float*)d_in[19];

  int N = in_sizes[0] / 128;
  int E = in_sizes[2] / 2;
  int NT = 2 * N;
  int nblk2 = (NT + 255) / 256;
  int NBUK = (NT + 127) / 128;

  char* ws = (char*)d_ws;
  size_t off = 0;
  auto alloc = [&](size_t bytes) -> void* {
    void* p = ws + off;
    off += (bytes + 511) & ~(size_t)511;
    return p;
  };
  float* agg = (float*)alloc((size_t)NT * 128 * 4);      // 102.4 MB
  int* ebuf = (int*)alloc((size_t)2 * E * 4);            // 12.8 MB
  int* cnt = (int*)alloc((size_t)NT * 4);
  int* rowptr = (int*)alloc((size_t)(NT + 1) * 4);
  int* part_i = (int*)alloc((size_t)1024 * 4);
  float* dinv = (float*)alloc((size_t)NT * 4);
  int* hist = (int*)alloc((size_t)PNB * NBUK * 4);
  int* offs = (int*)alloc((size_t)PNB * NBUK * 4);
  float* part = (float*)alloc((size_t)2 * BGRAPH * PPARTS * 128 * 4);
  int* start = (int*)alloc((size_t)(2 * BGRAPH + 1) * 4);
  float* g = (float*)alloc((size_t)2 * BGRAPH * 128 * 4);
  (void)ws_size; (void)n_in; (void)out_size;

  const int* src1 = ei1, *dst1 = ei1 + E;
  const int* src2 = ei2, *dst2 = ei2 + E;

  cnt_zero_kernel<<<nblk2, 256, 0, stream>>>(cnt, NT);
  count_kernel<<<(2 * E + 255) / 256, 256, 0, stream>>>(dst1, dst2, cnt, E, N);
  part_sum_kernel<<<nblk2, 256, 0, stream>>>(cnt, part_i, NT);
  part_scan_kernel<<<1, 1024, 0, stream>>>(part_i, nblk2);
  rowptr_kernel<<<nblk2, 256, 0, stream>>>(cnt, part_i, rowptr, dinv, NT, 2 * E);
  hist_kernel<<<PNB, 1024, 0, stream>>>(dst1, dst2, hist, E, N, NBUK);
  offs_kernel<<<NBUK, 64, 0, stream>>>(hist, rowptr, offs, NBUK);
  partition_kernel<<<PNB, 1024, 0, stream>>>(src1, dst1, src2, dst2, offs, ebuf, E, N, NBUK);
  bucket_sort_kernel<<<NBUK, 256, 0, stream>>>(ebuf, rowptr, NT);
  gather_kernel<<<(unsigned)(((size_t)NT * 32 + 255) / 256), 256, 0, stream>>>(
      x1, x2, ebuf, rowptr, dinv, agg, N, NT);
  int nbA = (N + GTILE - 1) / GTILE;
  gemm_tiled_kernel<<<2 * nbA, 256, 0, stream>>>(agg, agg, conv1W, conv1b,
                                                 conv2W, conv2b, N, NT, nbA);
  bounds_kernel<<<2, 256, 0, stream>>>(batch1, batch2, start, N, BGRAPH);
  pool_part_kernel<<<2 * BGRAPH * PPARTS, 128, 0, stream>>>(agg, start, part);
  pool_combine_kernel<<<2 * BGRAPH, 128, 0, stream>>>(part, g);

  head_kernel<<<BGRAPH, 256, 0, stream>>>(g, g + (size_t)BGRAPH * 128,
                                          fcp1W, fcp1b, fcp2W, fcp2b,
                                          fc1W, fc1b, fc2W, fc2b, outW, outb,
                                          (float*)d_out);
}

// Round 6
// 650.578 us; speedup vs baseline: 4.4033x; 1.2011x over previous
//
#include <hip/hip_runtime.h>
#include <math.h>

#define NSLOPE 0.01f
#define BGRAPH 128
#define GTILE 128
#define BK 32
#define PNB 64        // partition blocks
#define MAXBUK 2048   // >= (2N+127)/128
#define SCAP 4608     // bucket capacity (mean 2048, +56 sigma)

__device__ __forceinline__ float lrelu(float v) { return v >= 0.f ? v : NSLOPE * v; }

// order-preserving float->uint key (max via unsigned atomicMax); +0.0f kills -0.0
__device__ __forceinline__ unsigned fkey(float v) {
  v = v + 0.0f;
  unsigned b = __float_as_uint(v);
  return (b & 0x80000000u) ? ~b : (b | 0x80000000u);
}
__device__ __forceinline__ float fdec(unsigned k) {
  return __uint_as_float((k & 0x80000000u) ? (k ^ 0x80000000u) : ~k);
}
__device__ __forceinline__ unsigned bf16rne(float f) {
  unsigned b = __float_as_uint(f);
  return (b + 0x7fffu + ((b >> 16) & 1u)) >> 16;
}
__device__ __forceinline__ float4 bfunpack(uint2 w) {
  float4 f;
  f.x = __uint_as_float(w.x << 16);
  f.y = __uint_as_float(w.x & 0xffff0000u);
  f.z = __uint_as_float(w.y << 16);
  f.w = __uint_as_float(w.y & 0xffff0000u);
  return f;
}

// ---------- edge partition into 128-node buckets ----------

__global__ __launch_bounds__(1024) void hist_kernel(
    const int* __restrict__ dst1, const int* __restrict__ dst2,
    int* __restrict__ hist, int ne, int off, int nbuk) {
  __shared__ int h[MAXBUK];
  for (int i = threadIdx.x; i < nbuk; i += 1024) h[i] = 0;
  __syncthreads();
  int total = 2 * ne;
  int chunk = (total + gridDim.x - 1) / gridDim.x;
  int a = blockIdx.x * chunk;
  int b = min(total, a + chunk);
  for (int e = a + threadIdx.x; e < b; e += 1024) {
    int d = (e < ne) ? dst1[e] : dst2[e - ne] + off;
    atomicAdd(&h[d >> 7], 1);
  }
  __syncthreads();
  for (int i = threadIdx.x; i < nbuk; i += 1024)
    hist[blockIdx.x * nbuk + i] = h[i];
}

__global__ void colsum_kernel(const int* __restrict__ hist, int* __restrict__ colsum,
                              int nbuk) {
  int b = blockIdx.x, t = threadIdx.x;  // 64 threads
  int v = hist[t * nbuk + b];
  for (int o = 32; o > 0; o >>= 1) v += __shfl_down(v, o);
  if (t == 0) colsum[b] = v;
}

// exclusive scan over nbuk (<=2048) bucket totals; bbase[nbuk] = total edges
__global__ __launch_bounds__(1024) void bscan_kernel(
    const int* __restrict__ colsum, int* __restrict__ bbase, int nbuk, int total) {
  __shared__ int s[1024];
  int t = threadIdx.x;
  int a0 = (2 * t < nbuk) ? colsum[2 * t] : 0;
  int a1 = (2 * t + 1 < nbuk) ? colsum[2 * t + 1] : 0;
  int ps = a0 + a1;
  s[t] = ps;
  __syncthreads();
  for (int off = 1; off < 1024; off <<= 1) {
    int u = (t >= off) ? s[t - off] : 0;
    __syncthreads();
    s[t] += u;
    __syncthreads();
  }
  int excl = s[t] - ps;
  if (2 * t < nbuk) bbase[2 * t] = excl;
  if (2 * t + 1 < nbuk) bbase[2 * t + 1] = excl + a0;
  if (t == 0) bbase[nbuk] = total;
}

__global__ void offs_kernel(const int* __restrict__ hist, const int* __restrict__ bbase,
                            int* __restrict__ offs, int nbuk) {
  int b = blockIdx.x, t = threadIdx.x;  // 64 threads, one wave
  int v = hist[t * nbuk + b];
  int sum = v;
  for (int o = 1; o < 64; o <<= 1) {
    int u = __shfl_up(sum, o);
    if (t >= o) sum += u;
  }
  offs[t * nbuk + b] = bbase[b] + (sum - v);
}

__global__ __launch_bounds__(1024) void partition_kernel(
    const int* __restrict__ s1, const int* __restrict__ d1,
    const int* __restrict__ s2, const int* __restrict__ d2,
    const int* __restrict__ offs, int* __restrict__ ebuf,
    int ne, int off, int nbuk) {
  __shared__ int cur[MAXBUK];
  for (int i = threadIdx.x; i < nbuk; i += 1024)
    cur[i] = offs[blockIdx.x * nbuk + i];
  __syncthreads();
  int total = 2 * ne;
  int chunk = (total + gridDim.x - 1) / gridDim.x;
  int a = blockIdx.x * chunk;
  int b = min(total, a + chunk);
  for (int e = a + threadIdx.x; e < b; e += 1024) {
    int s, d;
    if (e < ne) { s = s1[e]; d = d1[e]; }
    else { s = s2[e - ne] + off; d = d2[e - ne] + off; }
    int p = atomicAdd(&cur[d >> 7], 1);
    ebuf[p] = (s << 7) | (d & 127);  // s < 2^18 -> fits 25 bits
  }
}

// counting-sort bucket edges by dst in LDS; also builds rowptr + dinv locally
__global__ __launch_bounds__(256) void bucket_sort_kernel(
    int* __restrict__ ebuf, const int* __restrict__ bbase,
    int* __restrict__ rowptr, float* __restrict__ dinv, int ntot, int nbuk) {
  __shared__ int buf[SCAP];
  __shared__ int outv[SCAP];
  __shared__ int h[128];
  __shared__ int sc[128];
  __shared__ int cur[128];
  int b = blockIdx.x, t = threadIdx.x;
  int v0 = b * 128;
  int e0 = bbase[b], e1 = bbase[b + 1];
  int cnt = e1 - e0;
  if (t < 128) h[t] = 0;
  for (int i = t; i < cnt; i += 256) buf[i] = ebuf[e0 + i];
  __syncthreads();
  for (int i = t; i < cnt; i += 256) atomicAdd(&h[buf[i] & 127], 1);
  __syncthreads();
  if (t < 128) sc[t] = h[t];
  __syncthreads();
  for (int off = 1; off < 128; off <<= 1) {
    int u = (t < 128 && t >= off) ? sc[t - off] : 0;
    __syncthreads();
    if (t < 128) sc[t] += u;
    __syncthreads();
  }
  if (t < 128) {
    int excl = sc[t] - h[t];
    cur[t] = excl;
    int v = v0 + t;
    if (v < ntot) {
      rowptr[v] = e0 + excl;
      dinv[v] = rsqrtf((float)(h[t] + 1));
    }
  }
  if (b == nbuk - 1 && t == 0) rowptr[ntot] = bbase[nbuk];
  __syncthreads();
  for (int i = t; i < cnt; i += 256) {
    int p = buf[i];
    int pos = atomicAdd(&cur[p & 127], 1);
    outv[pos] = p >> 7;
  }
  __syncthreads();
  for (int i = t; i < cnt; i += 256) ebuf[e0 + i] = outv[i];
}

// xh[v] = bf16(dinv[v] * x[v]), packed 4 bf16 per lane (uint2)
__global__ void xh_kernel(const float* __restrict__ x1, const float* __restrict__ x2,
                          const float* __restrict__ dinv, uint2* __restrict__ xh,
                          int n1, int ntot) {
  int tid = blockIdx.x * blockDim.x + threadIdx.x;
  int v = tid >> 5, l = tid & 31;
  if (v >= ntot) return;
  const float4* xr = (v < n1) ? (const float4*)(x1 + (size_t)v * 128)
                              : (const float4*)(x2 + (size_t)(v - n1) * 128);
  float4 xv = xr[l];
  float dv = dinv[v];
  unsigned b0 = bf16rne(dv * xv.x), b1 = bf16rne(dv * xv.y);
  unsigned b2 = bf16rne(dv * xv.z), b3 = bf16rne(dv * xv.w);
  uint2 w;
  w.x = (b1 << 16) | b0;
  w.y = (b3 << 16) | b2;
  xh[(size_t)v * 32 + l] = w;
}

// agg16[v] = bf16( dinv[v] * (xh[v] + sum_{s in N(v)} xh[s]) )
__global__ void gather_kernel(const uint2* __restrict__ xh, const int* __restrict__ csr,
                              const int* __restrict__ rowptr, const float* __restrict__ dinv,
                              uint2* __restrict__ agg16, int ntot) {
  int tid = blockIdx.x * blockDim.x + threadIdx.x;
  int v = tid >> 5, l = tid & 31;
  if (v >= ntot) return;
  float4 a0 = bfunpack(xh[(size_t)v * 32 + l]);  // self term (pre-scaled by dinv[v])
  float4 a1 = make_float4(0.f, 0.f, 0.f, 0.f);
  int rs = rowptr[v], re = rowptr[v + 1];
  int base = rs;
  for (; base + 32 <= re; base += 32) {
    int sown = csr[base + l];
#pragma unroll
    for (int j = 0; j < 32; j += 2) {
      int s0 = __shfl(sown, j, 32);
      int s1 = __shfl(sown, j + 1, 32);
      float4 f0 = bfunpack(xh[(size_t)s0 * 32 + l]);
      float4 f1 = bfunpack(xh[(size_t)s1 * 32 + l]);
      a0.x += f0.x; a0.y += f0.y; a0.z += f0.z; a0.w += f0.w;
      a1.x += f1.x; a1.y += f1.y; a1.z += f1.z; a1.w += f1.w;
    }
  }
  if (base < re) {
    int idx = base + l;
    int sown = (idx < re) ? csr[idx] : 0;
    int m = re - base;
    for (int j = 0; j < m; j++) {
      int s = __shfl(sown, j, 32);
      float4 f = bfunpack(xh[(size_t)s * 32 + l]);
      a0.x += f.x; a0.y += f.y; a0.z += f.z; a0.w += f.w;
    }
  }
  float dv = dinv[v];
  float fx = dv * (a0.x + a1.x), fy = dv * (a0.y + a1.y);
  float fz = dv * (a0.z + a1.z), fw = dv * (a0.w + a1.w);
  uint2 w;
  w.x = (bf16rne(fy) << 16) | bf16rne(fx);
  w.y = (bf16rne(fw) << 16) | bf16rne(fz);
  agg16[(size_t)v * 32 + l] = w;
}

// ---------- GEMM (bf16 A, fp32 W) with fused lrelu + segment-max epilogue ----------
__global__ __launch_bounds__(256, 3) void gemm_pool_kernel(
    const uint2* __restrict__ A16,
    const float* __restrict__ W1, const float* __restrict__ b1,
    const float* __restrict__ W2, const float* __restrict__ b2,
    const int* __restrict__ batch1, const int* __restrict__ batch2,
    unsigned* __restrict__ gbuf, int N1, int Ntot, int nbA) {
  __shared__ float xs[BK * 132];
  __shared__ float wsm[BK * 128];
  __shared__ int sgid[128];
  __shared__ unsigned lmax[8 * 128];
  __shared__ int s_span;
  int b = blockIdx.x;
  int half = (b >= nbA) ? 1 : 0;
  const float* W = half ? W2 : W1;
  const float* bias = half ? b2 : b1;
  int base = half ? (N1 + (b - nbA) * GTILE) : b * GTILE;
  int rmax = half ? Ntot : N1;
  int t = threadIdx.x;
  int tr = t & 15, tc = t >> 4;
  int r0 = tr * 8, c0 = tc * 8;

  float acc[8][8];
#pragma unroll
  for (int i = 0; i < 8; i++)
#pragma unroll
    for (int j = 0; j < 8; j++) acc[i][j] = 0.f;

  for (int kc = 0; kc < 128; kc += BK) {
#pragma unroll
    for (int i = 0; i < 4; i++) {
      int idx = t + i * 256;      // 0..1023
      int row = idx >> 3;         // 0..127
      int q = idx & 7;            // uint2 (4-elem) index within chunk
      int gr = base + row;
      uint2 w = make_uint2(0u, 0u);
      if (gr < rmax) w = A16[(size_t)gr * 32 + (kc >> 2) + q];
      float4 av = bfunpack(w);
      xs[(q * 4 + 0) * 132 + row] = av.x;
      xs[(q * 4 + 1) * 132 + row] = av.y;
      xs[(q * 4 + 2) * 132 + row] = av.z;
      xs[(q * 4 + 3) * 132 + row] = av.w;
    }
#pragma unroll
    for (int i = 0; i < 4; i++) {
      int idx = t + i * 256;
      int k = idx >> 5, c4 = idx & 31;
      ((float4*)wsm)[k * 32 + c4] = ((const float4*)(W + (size_t)(kc + k) * 128))[c4];
    }
    __syncthreads();
#pragma unroll 8
    for (int k = 0; k < BK; k++) {
      float4 a0v = *(const float4*)(xs + k * 132 + r0);
      float4 a1v = *(const float4*)(xs + k * 132 + r0 + 4);
      float4 w0 = *(const float4*)(wsm + k * 128 + c0);
      float4 w1 = *(const float4*)(wsm + k * 128 + c0 + 4);
      float av[8] = {a0v.x, a0v.y, a0v.z, a0v.w, a1v.x, a1v.y, a1v.z, a1v.w};
      float wv[8] = {w0.x, w0.y, w0.z, w0.w, w1.x, w1.y, w1.z, w1.w};
#pragma unroll
      for (int i = 0; i < 8; i++)
#pragma unroll
        for (int j = 0; j < 8; j++) acc[i][j] = fmaf(av[i], wv[j], acc[i][j]);
    }
    __syncthreads();
  }

  // ---- epilogue: lrelu + per-tile segment-max into gbuf (encoded uint) ----
  if (t < 128) {
    int gr = base + t;
    int gid = -1;
    if (gr < rmax) gid = half ? (BGRAPH + batch2[gr - N1]) : batch1[gr];
    sgid[t] = gid;
  }
  for (int i = t; i < 8 * 128; i += 256) lmax[i] = 0u;
  __syncthreads();
  int g0 = sgid[0];
  if (t == 0) {
    int mg = g0;
    for (int r = 127; r >= 0; r--) {
      if (sgid[r] >= 0) { mg = sgid[r]; break; }
    }
    s_span = mg - g0 + 1;
  }
  float bv[8];
#pragma unroll
  for (int j = 0; j < 8; j++) bv[j] = bias[c0 + j];
#pragma unroll
  for (int i = 0; i < 8; i++) {
    int gid = sgid[r0 + i];
    if (gid < 0) continue;
    int loc = gid - g0;
#pragma unroll
    for (int j = 0; j < 8; j++) {
      unsigned key = fkey(lrelu(acc[i][j] + bv[j]));
      if (loc < 8) atomicMax(&lmax[loc * 128 + c0 + j], key);
      else atomicMax(&gbuf[(size_t)gid * 128 + c0 + j], key);
    }
  }
  __syncthreads();
  int span = s_span; if (span > 8) span = 8;
  for (int i = t; i < span * 128; i += 256) {
    unsigned k = lmax[i];
    if (k) atomicMax(&gbuf[(size_t)(g0 + (i >> 7)) * 128 + (i & 127)], k);
  }
}

__global__ void ginit_kernel(unsigned* __restrict__ gbuf, int n) {
  int i = blockIdx.x * blockDim.x + threadIdx.x;
  if (i < n) gbuf[i] = 0u;
}

// ---------- fused head (decodes pooled g) ----------

__global__ __launch_bounds__(256) void head_kernel(
    const unsigned* __restrict__ gbuf,
    const float* __restrict__ fcp1W, const float* __restrict__ fcp1b,
    const float* __restrict__ fcp2W, const float* __restrict__ fcp2b,
    const float* __restrict__ fc1W, const float* __restrict__ fc1b,
    const float* __restrict__ fc2W, const float* __restrict__ fc2b,
    const float* __restrict__ outW, const float* __restrict__ outb,
    float* __restrict__ out) {
  __shared__ float grow[256];
  __shared__ float c[256];
  __shared__ float h1[256];
  __shared__ float h2[64];
  int b = blockIdx.x, t = threadIdx.x;
  grow[t] = (t < 128) ? fdec(gbuf[(size_t)b * 128 + t])
                      : fdec(gbuf[(size_t)(BGRAPH + b) * 128 + (t - 128)]);
  __syncthreads();
  {
    float acc;
    if (t < 128) {
      acc = fcp1b[t];
      for (int k = 0; k < 128; k++) acc = fmaf(grow[k], fcp1W[k * 128 + t], acc);
    } else {
      int tc = t - 128;
      acc = fcp2b[tc];
      for (int k = 0; k < 128; k++) acc = fmaf(grow[128 + k], fcp2W[k * 128 + tc], acc);
    }
    c[t] = lrelu(acc);
  }
  __syncthreads();
  {
    float acc = fc1b[t];
    for (int k = 0; k < 256; k++) acc = fmaf(c[k], fc1W[k * 256 + t], acc);
    h1[t] = lrelu(acc);
  }
  __syncthreads();
  if (t < 64) {
    float acc = fc2b[t];
    for (int k = 0; k < 256; k++) acc = fmaf(h1[k], fc2W[k * 64 + t], acc);
    h2[t] = lrelu(acc);
  }
  __syncthreads();
  if (t < 64) {
    float v = h2[t] * outW[t];
    for (int off = 32; off > 0; off >>= 1) v += __shfl_down(v, off);
    if (t == 0) out[b] = 1.f / (1.f + expf(-(v + outb[0])));
  }
}

extern "C" void kernel_launch(void* const* d_in, const int* in_sizes, int n_in,
                              void* d_out, int out_size, void* d_ws, size_t ws_size,
                              hipStream_t stream) {
  const float* x1 = (const float*)d_in[0];
  const float* x2 = (const float*)d_in[1];
  const int* ei1 = (const int*)d_in[2];
  const int* ei2 = (const int*)d_in[3];
  const int* batch1 = (const int*)d_in[4];
  const int* batch2 = (const int*)d_in[5];
  const float* conv1W = (const float*)d_in[6];
  const float* conv1b = (const float*)d_in[7];
  const float* conv2W = (const float*)d_in[8];
  const float* conv2b = (const float*)d_in[9];
  const float* fcp1W = (const float*)d_in[10];
  const float* fcp1b = (const float*)d_in[11];
  const float* fcp2W = (const float*)d_in[12];
  const float* fcp2b = (const float*)d_in[13];
  const float* fc1W = (const float*)d_in[14];
  const float* fc1b = (const float*)d_in[15];
  const float* fc2W = (const float*)d_in[16];
  const float* fc2b = (const float*)d_in[17];
  const float* outW = (const float*)d_in[18];
  const float* outb = (const float*)d_in[19];

  int N = in_sizes[0] / 128;
  int E = in_sizes[2] / 2;
  int NT = 2 * N;
  int NBUK = (NT + 127) / 128;

  char* ws = (char*)d_ws;
  size_t off = 0;
  auto alloc = [&](size_t bytes) -> void* {
    void* p = ws + off;
    off += (bytes + 511) & ~(size_t)511;
    return p;
  };
  uint2* xh = (uint2*)alloc((size_t)NT * 256);         // 51.2 MB bf16 features
  uint2* agg16 = (uint2*)alloc((size_t)NT * 256);      // 51.2 MB bf16 agg
  int* ebuf = (int*)alloc((size_t)2 * E * 4);          // 12.8 MB
  int* rowptr = (int*)alloc((size_t)(NT + 1) * 4);
  float* dinv = (float*)alloc((size_t)NT * 4);
  int* hist = (int*)alloc((size_t)PNB * NBUK * 4);
  int* offs = (int*)alloc((size_t)PNB * NBUK * 4);
  int* colsum = (int*)alloc((size_t)NBUK * 4);
  int* bbase = (int*)alloc((size_t)(NBUK + 1) * 4);
  unsigned* gbuf = (unsigned*)alloc((size_t)2 * BGRAPH * 128 * 4);
  (void)ws_size; (void)n_in; (void)out_size;

  const int* src1 = ei1, *dst1 = ei1 + E;
  const int* src2 = ei2, *dst2 = ei2 + E;

  hist_kernel<<<PNB, 1024, 0, stream>>>(dst1, dst2, hist, E, N, NBUK);
  colsum_kernel<<<NBUK, 64, 0, stream>>>(hist, colsum, NBUK);
  bscan_kernel<<<1, 1024, 0, stream>>>(colsum, bbase, NBUK, 2 * E);
  offs_kernel<<<NBUK, 64, 0, stream>>>(hist, bbase, offs, NBUK);
  partition_kernel<<<PNB, 1024, 0, stream>>>(src1, dst1, src2, dst2, offs, ebuf, E, N, NBUK);
  bucket_sort_kernel<<<NBUK, 256, 0, stream>>>(ebuf, bbase, rowptr, dinv, NT, NBUK);
  xh_kernel<<<(unsigned)(((size_t)NT * 32 + 255) / 256), 256, 0, stream>>>(
      x1, x2, dinv, xh, N, NT);
  gather_kernel<<<(unsigned)(((size_t)NT * 32 + 255) / 256), 256, 0, stream>>>(
      xh, ebuf, rowptr, dinv, agg16, NT);
  ginit_kernel<<<(2 * BGRAPH * 128 + 255) / 256, 256, 0, stream>>>(gbuf, 2 * BGRAPH * 128);
  int nbA = (N + GTILE - 1) / GTILE;
  gemm_pool_kernel<<<2 * nbA, 256, 0, stream>>>(agg16, conv1W, conv1b, conv2W, conv2b,
                                                batch1, batch2, gbuf, N, NT, nbA);
  head_kernel<<<BGRAPH, 256, 0, stream>>>(gbuf, fcp1W, fcp1b, fcp2W, fcp2b,
                                          fc1W, fc1b, fc2W, fc2b, outW, outb,
                                          (float*)d_out);
}

// Round 8
// 623.440 us; speedup vs baseline: 4.5949x; 1.0435x over previous
//
#include <hip/hip_runtime.h>
#include <math.h>

#define NSLOPE 0.01f
#define BGRAPH 128
#define GTILE 128
#define BK 32
#define PNB 64        // partition blocks
#define MAXBUK 2048   // >= (2N+127)/128
#define SCAP 4608     // bucket capacity (mean 2048, +56 sigma)

typedef unsigned int uv4 __attribute__((ext_vector_type(4)));

__device__ __forceinline__ float lrelu(float v) { return v >= 0.f ? v : NSLOPE * v; }

// order-preserving float->uint key (max via unsigned atomicMax); +0.0f kills -0.0
__device__ __forceinline__ unsigned fkey(float v) {
  v = v + 0.0f;
  unsigned b = __float_as_uint(v);
  return (b & 0x80000000u) ? ~b : (b | 0x80000000u);
}
__device__ __forceinline__ float fdec(unsigned k) {
  return __uint_as_float((k & 0x80000000u) ? (k ^ 0x80000000u) : ~k);
}
__device__ __forceinline__ unsigned bf16rne(float f) {
  unsigned b = __float_as_uint(f);
  return (b + 0x7fffu + ((b >> 16) & 1u)) >> 16;
}
__device__ __forceinline__ float4 bfunpack(uint2 w) {
  float4 f;
  f.x = __uint_as_float(w.x << 16);
  f.y = __uint_as_float(w.x & 0xffff0000u);
  f.z = __uint_as_float(w.y << 16);
  f.w = __uint_as_float(w.y & 0xffff0000u);
  return f;
}
__device__ __forceinline__ void bfunpack8(uint4 w, float4& lo, float4& hi) {
  lo.x = __uint_as_float(w.x << 16); lo.y = __uint_as_float(w.x & 0xffff0000u);
  lo.z = __uint_as_float(w.y << 16); lo.w = __uint_as_float(w.y & 0xffff0000u);
  hi.x = __uint_as_float(w.z << 16); hi.y = __uint_as_float(w.z & 0xffff0000u);
  hi.z = __uint_as_float(w.w << 16); hi.w = __uint_as_float(w.w & 0xffff0000u);
}
__device__ __forceinline__ void add8(float4& alo, float4& ahi, const float4 lo, const float4 hi) {
  alo.x += lo.x; alo.y += lo.y; alo.z += lo.z; alo.w += lo.w;
  ahi.x += hi.x; ahi.y += hi.y; ahi.z += hi.z; ahi.w += hi.w;
}

// ---------- edge partition into 128-node buckets ----------

__global__ __launch_bounds__(1024) void hist_kernel(
    const int* __restrict__ dst1, const int* __restrict__ dst2,
    int* __restrict__ hist, int ne, int off, int nbuk) {
  __shared__ int h[MAXBUK];
  for (int i = threadIdx.x; i < nbuk; i += 1024) h[i] = 0;
  __syncthreads();
  int total = 2 * ne;
  int chunk = (total + gridDim.x - 1) / gridDim.x;
  int a = blockIdx.x * chunk;
  int b = min(total, a + chunk);
  for (int e = a + threadIdx.x; e < b; e += 1024) {
    int d = (e < ne) ? dst1[e] : dst2[e - ne] + off;
    atomicAdd(&h[d >> 7], 1);
  }
  __syncthreads();
  for (int i = threadIdx.x; i < nbuk; i += 1024)
    hist[blockIdx.x * nbuk + i] = h[i];
}

__global__ void colsum_kernel(const int* __restrict__ hist, int* __restrict__ colsum,
                              int nbuk) {
  int b = blockIdx.x, t = threadIdx.x;  // 64 threads
  int v = hist[t * nbuk + b];
  for (int o = 32; o > 0; o >>= 1) v += __shfl_down(v, o);
  if (t == 0) colsum[b] = v;
}

// exclusive scan over nbuk (<=2048) bucket totals; bbase[nbuk] = total edges
__global__ __launch_bounds__(1024) void bscan_kernel(
    const int* __restrict__ colsum, int* __restrict__ bbase, int nbuk, int total) {
  __shared__ int s[1024];
  int t = threadIdx.x;
  int a0 = (2 * t < nbuk) ? colsum[2 * t] : 0;
  int a1 = (2 * t + 1 < nbuk) ? colsum[2 * t + 1] : 0;
  int ps = a0 + a1;
  s[t] = ps;
  __syncthreads();
  for (int off = 1; off < 1024; off <<= 1) {
    int u = (t >= off) ? s[t - off] : 0;
    __syncthreads();
    s[t] += u;
    __syncthreads();
  }
  int excl = s[t] - ps;
  if (2 * t < nbuk) bbase[2 * t] = excl;
  if (2 * t + 1 < nbuk) bbase[2 * t + 1] = excl + a0;
  if (t == 0) bbase[nbuk] = total;
}

__global__ void offs_kernel(const int* __restrict__ hist, const int* __restrict__ bbase,
                            int* __restrict__ offs, int nbuk) {
  int b = blockIdx.x, t = threadIdx.x;  // 64 threads, one wave
  int v = hist[t * nbuk + b];
  int sum = v;
  for (int o = 1; o < 64; o <<= 1) {
    int u = __shfl_up(sum, o);
    if (t >= o) sum += u;
  }
  offs[t * nbuk + b] = bbase[b] + (sum - v);
}

__global__ __launch_bounds__(1024) void partition_kernel(
    const int* __restrict__ s1, const int* __restrict__ d1,
    const int* __restrict__ s2, const int* __restrict__ d2,
    const int* __restrict__ offs, int* __restrict__ ebuf,
    int ne, int off, int nbuk) {
  __shared__ int cur[MAXBUK];
  for (int i = threadIdx.x; i < nbuk; i += 1024)
    cur[i] = offs[blockIdx.x * nbuk + i];
  __syncthreads();
  int total = 2 * ne;
  int chunk = (total + gridDim.x - 1) / gridDim.x;
  int a = blockIdx.x * chunk;
  int b = min(total, a + chunk);
  for (int e = a + threadIdx.x; e < b; e += 1024) {
    int s, d;
    if (e < ne) { s = s1[e]; d = d1[e]; }
    else { s = s2[e - ne] + off; d = d2[e - ne] + off; }
    int p = atomicAdd(&cur[d >> 7], 1);
    ebuf[p] = (s << 7) | (d & 127);  // s < 2^18 -> fits 25 bits
  }
}

// counting-sort bucket edges by dst in LDS; also builds rowptr + dinv locally
__global__ __launch_bounds__(256) void bucket_sort_kernel(
    int* __restrict__ ebuf, const int* __restrict__ bbase,
    int* __restrict__ rowptr, float* __restrict__ dinv, int ntot, int nbuk) {
  __shared__ int buf[SCAP];
  __shared__ int outv[SCAP];
  __shared__ int h[128];
  __shared__ int sc[128];
  __shared__ int cur[128];
  int b = blockIdx.x, t = threadIdx.x;
  int v0 = b * 128;
  int e0 = bbase[b], e1 = bbase[b + 1];
  int cnt = e1 - e0;
  if (t < 128) h[t] = 0;
  for (int i = t; i < cnt; i += 256) buf[i] = ebuf[e0 + i];
  __syncthreads();
  for (int i = t; i < cnt; i += 256) atomicAdd(&h[buf[i] & 127], 1);
  __syncthreads();
  if (t < 128) sc[t] = h[t];
  __syncthreads();
  for (int off = 1; off < 128; off <<= 1) {
    int u = (t < 128 && t >= off) ? sc[t - off] : 0;
    __syncthreads();
    if (t < 128) sc[t] += u;
    __syncthreads();
  }
  if (t < 128) {
    int excl = sc[t] - h[t];
    cur[t] = excl;
    int v = v0 + t;
    if (v < ntot) {
      rowptr[v] = e0 + excl;
      dinv[v] = rsqrtf((float)(h[t] + 1));
    }
  }
  if (b == nbuk - 1 && t == 0) rowptr[ntot] = bbase[nbuk];
  __syncthreads();
  for (int i = t; i < cnt; i += 256) {
    int p = buf[i];
    int pos = atomicAdd(&cur[p & 127], 1);
    outv[pos] = p >> 7;
  }
  __syncthreads();
  for (int i = t; i < cnt; i += 256) ebuf[e0 + i] = outv[i];
}

// xh[v] = bf16(dinv[v] * x[v]), packed 4 bf16 per lane (uint2)
__global__ void xh_kernel(const float* __restrict__ x1, const float* __restrict__ x2,
                          const float* __restrict__ dinv, uint2* __restrict__ xh,
                          int n1, int ntot) {
  int tid = blockIdx.x * blockDim.x + threadIdx.x;
  int v = tid >> 5, l = tid & 31;
  if (v >= ntot) return;
  const float4* xr = (v < n1) ? (const float4*)(x1 + (size_t)v * 128)
                              : (const float4*)(x2 + (size_t)(v - n1) * 128);
  float4 xv = xr[l];
  float dv = dinv[v];
  unsigned b0 = bf16rne(dv * xv.x), b1 = bf16rne(dv * xv.y);
  unsigned b2 = bf16rne(dv * xv.z), b3 = bf16rne(dv * xv.w);
  uint2 w;
  w.x = (b1 << 16) | b0;
  w.y = (b3 << 16) | b2;
  xh[(size_t)v * 32 + l] = w;
}

// agg16[v] = bf16( dinv[v] * (xh[v] + sum_{s in N(v)} xh[s]) )
// 16 lanes per node, uint4 (8 bf16) per lane; 4-deep unrolled gather.
__global__ __launch_bounds__(256) void gather_kernel(
    const uint4* __restrict__ xh, const int* __restrict__ csr,
    const int* __restrict__ rowptr, const float* __restrict__ dinv,
    uv4* __restrict__ agg16, int ntot) {
  int tid = blockIdx.x * blockDim.x + threadIdx.x;
  int v = tid >> 4, l = tid & 15;
  if (v >= ntot) return;
  float4 a0, a1, b0, b1, c0, c1, d0, d1;
  bfunpack8(xh[(size_t)v * 16 + l], a0, a1);  // self term (pre-scaled by dinv[v])
  b0 = make_float4(0.f, 0.f, 0.f, 0.f); b1 = b0;
  c0 = b0; c1 = b0; d0 = b0; d1 = b0;
  int rs = __builtin_nontemporal_load(&rowptr[v]);
  int re = __builtin_nontemporal_load(&rowptr[v + 1]);
  int base = rs;
  for (; base + 16 <= re; base += 16) {
    int sown = __builtin_nontemporal_load(&csr[base + l]);
#pragma unroll
    for (int j = 0; j < 16; j += 4) {
      int s0 = __shfl(sown, j, 16);
      int s1 = __shfl(sown, j + 1, 16);
      int s2 = __shfl(sown, j + 2, 16);
      int s3 = __shfl(sown, j + 3, 16);
      uint4 w0 = xh[(size_t)s0 * 16 + l];
      uint4 w1 = xh[(size_t)s1 * 16 + l];
      uint4 w2 = xh[(size_t)s2 * 16 + l];
      uint4 w3 = xh[(size_t)s3 * 16 + l];
      float4 lo, hi;
      bfunpack8(w0, lo, hi); add8(a0, a1, lo, hi);
      bfunpack8(w1, lo, hi); add8(b0, b1, lo, hi);
      bfunpack8(w2, lo, hi); add8(c0, c1, lo, hi);
      bfunpack8(w3, lo, hi); add8(d0, d1, lo, hi);
    }
  }
  if (base < re) {
    int idx = base + l;
    int sown = (idx < re) ? __builtin_nontemporal_load(&csr[idx]) : 0;
    int m = re - base;
    for (int j = 0; j < m; j++) {
      int s = __shfl(sown, j, 16);
      float4 lo, hi;
      bfunpack8(xh[(size_t)s * 16 + l], lo, hi);
      add8(a0, a1, lo, hi);
    }
  }
  add8(a0, a1, b0, b1);
  add8(c0, c1, d0, d1);
  add8(a0, a1, c0, c1);
  float dv = dinv[v];
  uv4 w;
  w.x = (bf16rne(dv * a0.y) << 16) | bf16rne(dv * a0.x);
  w.y = (bf16rne(dv * a0.w) << 16) | bf16rne(dv * a0.z);
  w.z = (bf16rne(dv * a1.y) << 16) | bf16rne(dv * a1.x);
  w.w = (bf16rne(dv * a1.w) << 16) | bf16rne(dv * a1.z);
  __builtin_nontemporal_store(w, &agg16[(size_t)v * 16 + l]);
}

// ---------- GEMM (bf16 A, fp32 W) with fused lrelu + segment-max epilogue ----------
__global__ __launch_bounds__(256, 3) void gemm_pool_kernel(
    const uint2* __restrict__ A16,
    const float* __restrict__ W1, const float* __restrict__ b1,
    const float* __restrict__ W2, const float* __restrict__ b2,
    const int* __restrict__ batch1, const int* __restrict__ batch2,
    unsigned* __restrict__ gbuf, int N1, int Ntot, int nbA) {
  __shared__ float xs[BK * 132];
  __shared__ float wsm[BK * 128];
  __shared__ int sgid[128];
  __shared__ unsigned lmax[8 * 128];
  __shared__ int s_span;
  int b = blockIdx.x;
  int half = (b >= nbA) ? 1 : 0;
  const float* W = half ? W2 : W1;
  const float* bias = half ? b2 : b1;
  int base = half ? (N1 + (b - nbA) * GTILE) : b * GTILE;
  int rmax = half ? Ntot : N1;
  int t = threadIdx.x;
  int tr = t & 15, tc = t >> 4;
  int r0 = tr * 8, c0 = tc * 8;

  float acc[8][8];
#pragma unroll
  for (int i = 0; i < 8; i++)
#pragma unroll
    for (int j = 0; j < 8; j++) acc[i][j] = 0.f;

  for (int kc = 0; kc < 128; kc += BK) {
#pragma unroll
    for (int i = 0; i < 4; i++) {
      int idx = t + i * 256;      // 0..1023
      int row = idx >> 3;         // 0..127
      int q = idx & 7;            // uint2 (4-elem) index within chunk
      int gr = base + row;
      uint2 w = make_uint2(0u, 0u);
      if (gr < rmax) w = A16[(size_t)gr * 32 + (kc >> 2) + q];
      float4 av = bfunpack(w);
      xs[(q * 4 + 0) * 132 + row] = av.x;
      xs[(q * 4 + 1) * 132 + row] = av.y;
      xs[(q * 4 + 2) * 132 + row] = av.z;
      xs[(q * 4 + 3) * 132 + row] = av.w;
    }
#pragma unroll
    for (int i = 0; i < 4; i++) {
      int idx = t + i * 256;
      int k = idx >> 5, c4 = idx & 31;
      ((float4*)wsm)[k * 32 + c4] = ((const float4*)(W + (size_t)(kc + k) * 128))[c4];
    }
    __syncthreads();
#pragma unroll 8
    for (int k = 0; k < BK; k++) {
      float4 a0v = *(const float4*)(xs + k * 132 + r0);
      float4 a1v = *(const float4*)(xs + k * 132 + r0 + 4);
      float4 w0 = *(const float4*)(wsm + k * 128 + c0);
      float4 w1 = *(const float4*)(wsm + k * 128 + c0 + 4);
      float av[8] = {a0v.x, a0v.y, a0v.z, a0v.w, a1v.x, a1v.y, a1v.z, a1v.w};
      float wv[8] = {w0.x, w0.y, w0.z, w0.w, w1.x, w1.y, w1.z, w1.w};
#pragma unroll
      for (int i = 0; i < 8; i++)
#pragma unroll
        for (int j = 0; j < 8; j++) acc[i][j] = fmaf(av[i], wv[j], acc[i][j]);
    }
    __syncthreads();
  }

  // ---- epilogue: lrelu + per-tile segment-max into gbuf (encoded uint) ----
  if (t < 128) {
    int gr = base + t;
    int gid = -1;
    if (gr < rmax) gid = half ? (BGRAPH + batch2[gr - N1]) : batch1[gr];
    sgid[t] = gid;
  }
  for (int i = t; i < 8 * 128; i += 256) lmax[i] = 0u;
  __syncthreads();
  int g0 = sgid[0];
  if (t == 0) {
    int mg = g0;
    for (int r = 127; r >= 0; r--) {
      if (sgid[r] >= 0) { mg = sgid[r]; break; }
    }
    s_span = mg - g0 + 1;
  }
  float bv[8];
#pragma unroll
  for (int j = 0; j < 8; j++) bv[j] = bias[c0 + j];
#pragma unroll
  for (int i = 0; i < 8; i++) {
    int gid = sgid[r0 + i];
    if (gid < 0) continue;
    int loc = gid - g0;
#pragma unroll
    for (int j = 0; j < 8; j++) {
      unsigned key = fkey(lrelu(acc[i][j] + bv[j]));
      if (loc < 8) atomicMax(&lmax[loc * 128 + c0 + j], key);
      else atomicMax(&gbuf[(size_t)gid * 128 + c0 + j], key);
    }
  }
  __syncthreads();
  int span = s_span; if (span > 8) span = 8;
  for (int i = t; i < span * 128; i += 256) {
    unsigned k = lmax[i];
    if (k) atomicMax(&gbuf[(size_t)(g0 + (i >> 7)) * 128 + (i & 127)], k);
  }
}

__global__ void ginit_kernel(unsigned* __restrict__ gbuf, int n) {
  int i = blockIdx.x * blockDim.x + threadIdx.x;
  if (i < n) gbuf[i] = 0u;
}

// ---------- fused head (decodes pooled g) ----------

__global__ __launch_bounds__(256) void head_kernel(
    const unsigned* __restrict__ gbuf,
    const float* __restrict__ fcp1W, const float* __restrict__ fcp1b,
    const float* __restrict__ fcp2W, const float* __restrict__ fcp2b,
    const float* __restrict__ fc1W, const float* __restrict__ fc1b,
    const float* __restrict__ fc2W, const float* __restrict__ fc2b,
    const float* __restrict__ outW, const float* __restrict__ outb,
    float* __restrict__ out) {
  __shared__ float grow[256];
  __shared__ float c[256];
  __shared__ float h1[256];
  __shared__ float h2[64];
  int b = blockIdx.x, t = threadIdx.x;
  grow[t] = (t < 128) ? fdec(gbuf[(size_t)b * 128 + t])
                      : fdec(gbuf[(size_t)(BGRAPH + b) * 128 + (t - 128)]);
  __syncthreads();
  {
    float acc;
    if (t < 128) {
      acc = fcp1b[t];
      for (int k = 0; k < 128; k++) acc = fmaf(grow[k], fcp1W[k * 128 + t], acc);
    } else {
      int tc = t - 128;
      acc = fcp2b[tc];
      for (int k = 0; k < 128; k++) acc = fmaf(grow[128 + k], fcp2W[k * 128 + tc], acc);
    }
    c[t] = lrelu(acc);
  }
  __syncthreads();
  {
    float acc = fc1b[t];
    for (int k = 0; k < 256; k++) acc = fmaf(c[k], fc1W[k * 256 + t], acc);
    h1[t] = lrelu(acc);
  }
  __syncthreads();
  if (t < 64) {
    float acc = fc2b[t];
    for (int k = 0; k < 256; k++) acc = fmaf(h1[k], fc2W[k * 64 + t], acc);
    h2[t] = lrelu(acc);
  }
  __syncthreads();
  if (t < 64) {
    float v = h2[t] * outW[t];
    for (int off = 32; off > 0; off >>= 1) v += __shfl_down(v, off);
    if (t == 0) out[b] = 1.f / (1.f + expf(-(v + outb[0])));
  }
}

extern "C" void kernel_launch(void* const* d_in, const int* in_sizes, int n_in,
                              void* d_out, int out_size, void* d_ws, size_t ws_size,
                              hipStream_t stream) {
  const float* x1 = (const float*)d_in[0];
  const float* x2 = (const float*)d_in[1];
  const int* ei1 = (const int*)d_in[2];
  const int* ei2 = (const int*)d_in[3];
  const int* batch1 = (const int*)d_in[4];
  const int* batch2 = (const int*)d_in[5];
  const float* conv1W = (const float*)d_in[6];
  const float* conv1b = (const float*)d_in[7];
  const float* conv2W = (const float*)d_in[8];
  const float* conv2b = (const float*)d_in[9];
  const float* fcp1W = (const float*)d_in[10];
  const float* fcp1b = (const float*)d_in[11];
  const float* fcp2W = (const float*)d_in[12];
  const float* fcp2b = (const float*)d_in[13];
  const float* fc1W = (const float*)d_in[14];
  const float* fc1b = (const float*)d_in[15];
  const float* fc2W = (const float*)d_in[16];
  const float* fc2b = (const float*)d_in[17];
  const float* outW = (const float*)d_in[18];
  const float* outb = (const float*)d_in[19];

  int N = in_sizes[0] / 128;
  int E = in_sizes[2] / 2;
  int NT = 2 * N;
  int NBUK = (NT + 127) / 128;

  char* ws = (char*)d_ws;
  size_t off = 0;
  auto alloc = [&](size_t bytes) -> void* {
    void* p = ws + off;
    off += (bytes + 511) & ~(size_t)511;
    return p;
  };
  uint2* xh = (uint2*)alloc((size_t)NT * 256);         // 51.2 MB bf16 features
  uint2* agg16 = (uint2*)alloc((size_t)NT * 256);      // 51.2 MB bf16 agg
  int* ebuf = (int*)alloc((size_t)2 * E * 4);          // 12.8 MB
  int* rowptr = (int*)alloc((size_t)(NT + 1) * 4);
  float* dinv = (float*)alloc((size_t)NT * 4);
  int* hist = (int*)alloc((size_t)PNB * NBUK * 4);
  int* offs = (int*)alloc((size_t)PNB * NBUK * 4);
  int* colsum = (int*)alloc((size_t)NBUK * 4);
  int* bbase = (int*)alloc((size_t)(NBUK + 1) * 4);
  unsigned* gbuf = (unsigned*)alloc((size_t)2 * BGRAPH * 128 * 4);
  (void)ws_size; (void)n_in; (void)out_size;

  const int* src1 = ei1, *dst1 = ei1 + E;
  const int* src2 = ei2, *dst2 = ei2 + E;

  hist_kernel<<<PNB, 1024, 0, stream>>>(dst1, dst2, hist, E, N, NBUK);
  colsum_kernel<<<NBUK, 64, 0, stream>>>(hist, colsum, NBUK);
  bscan_kernel<<<1, 1024, 0, stream>>>(colsum, bbase, NBUK, 2 * E);
  offs_kernel<<<NBUK, 64, 0, stream>>>(hist, bbase, offs, NBUK);
  partition_kernel<<<PNB, 1024, 0, stream>>>(src1, dst1, src2, dst2, offs, ebuf, E, N, NBUK);
  bucket_sort_kernel<<<NBUK, 256, 0, stream>>>(ebuf, bbase, rowptr, dinv, NT, NBUK);
  xh_kernel<<<(unsigned)(((size_t)NT * 32 + 255) / 256), 256, 0, stream>>>(
      x1, x2, dinv, xh, N, NT);
  gather_kernel<<<(unsigned)(((size_t)NT * 16 + 255) / 256), 256, 0, stream>>>(
      (const uint4*)xh, ebuf, rowptr, dinv, (uv4*)agg16, NT);
  ginit_kernel<<<(2 * BGRAPH * 128 + 255) / 256, 256, 0, stream>>>(gbuf, 2 * BGRAPH * 128);
  int nbA = (N + GTILE - 1) / GTILE;
  gemm_pool_kernel<<<2 * nbA, 256, 0, stream>>>(agg16, conv1W, conv1b, conv2W, conv2b,
                                                batch1, batch2, gbuf, N, NT, nbA);
  head_kernel<<<BGRAPH, 256, 0, stream>>>(gbuf, fcp1W, fcp1b, fcp2W, fcp2b,
                                          fc1W, fc1b, fc2W, fc2b, outW, outb,
                                          (float*)d_out);
}

// Round 9
// 558.534 us; speedup vs baseline: 5.1289x; 1.1162x over previous
//
#include <hip/hip_runtime.h>
#include <math.h>

#define NSLOPE 0.01f
#define BGRAPH 128
#define GTILE 128
#define PNB 64        // partition blocks
#define MAXBUK 2048   // >= (2N+127)/128
#define SCAP 4608     // bucket capacity (mean 2048, +56 sigma)

typedef unsigned int uv4 __attribute__((ext_vector_type(4)));
typedef short bf16x8 __attribute__((ext_vector_type(8)));
typedef float f32x4 __attribute__((ext_vector_type(4)));

__device__ __forceinline__ float lrelu(float v) { return v >= 0.f ? v : NSLOPE * v; }

// order-preserving float->uint key (max via unsigned atomicMax); +0.0f kills -0.0
__device__ __forceinline__ unsigned fkey(float v) {
  v = v + 0.0f;
  unsigned b = __float_as_uint(v);
  return (b & 0x80000000u) ? ~b : (b | 0x80000000u);
}
__device__ __forceinline__ float fdec(unsigned k) {
  return __uint_as_float((k & 0x80000000u) ? (k ^ 0x80000000u) : ~k);
}
__device__ __forceinline__ unsigned bf16rne(float f) {
  unsigned b = __float_as_uint(f);
  return (b + 0x7fffu + ((b >> 16) & 1u)) >> 16;
}
__device__ __forceinline__ void bfunpack8(uint4 w, float4& lo, float4& hi) {
  lo.x = __uint_as_float(w.x << 16); lo.y = __uint_as_float(w.x & 0xffff0000u);
  lo.z = __uint_as_float(w.y << 16); lo.w = __uint_as_float(w.y & 0xffff0000u);
  hi.x = __uint_as_float(w.z << 16); hi.y = __uint_as_float(w.z & 0xffff0000u);
  hi.z = __uint_as_float(w.w << 16); hi.w = __uint_as_float(w.w & 0xffff0000u);
}
__device__ __forceinline__ void add8(float4& alo, float4& ahi, const float4 lo, const float4 hi) {
  alo.x += lo.x; alo.y += lo.y; alo.z += lo.z; alo.w += lo.w;
  ahi.x += hi.x; ahi.y += hi.y; ahi.z += hi.z; ahi.w += hi.w;
}

// ---------- edge partition into 128-node buckets ----------

__global__ __launch_bounds__(1024) void hist_kernel(
    const int* __restrict__ dst1, const int* __restrict__ dst2,
    int* __restrict__ hist, int ne, int off, int nbuk) {
  __shared__ int h[MAXBUK];
  for (int i = threadIdx.x; i < nbuk; i += 1024) h[i] = 0;
  __syncthreads();
  int total = 2 * ne;
  int chunk = (total + gridDim.x - 1) / gridDim.x;
  int a = blockIdx.x * chunk;
  int b = min(total, a + chunk);
  for (int e = a + threadIdx.x; e < b; e += 1024) {
    int d = (e < ne) ? dst1[e] : dst2[e - ne] + off;
    atomicAdd(&h[d >> 7], 1);
  }
  __syncthreads();
  for (int i = threadIdx.x; i < nbuk; i += 1024)
    hist[blockIdx.x * nbuk + i] = h[i];
}

__global__ void colsum_kernel(const int* __restrict__ hist, int* __restrict__ colsum,
                              int nbuk) {
  int b = blockIdx.x, t = threadIdx.x;  // 64 threads
  int v = hist[t * nbuk + b];
  for (int o = 32; o > 0; o >>= 1) v += __shfl_down(v, o);
  if (t == 0) colsum[b] = v;
}

// exclusive scan over nbuk (<=2048) bucket totals; bbase[nbuk] = total edges
__global__ __launch_bounds__(1024) void bscan_kernel(
    const int* __restrict__ colsum, int* __restrict__ bbase, int nbuk, int total) {
  __shared__ int s[1024];
  int t = threadIdx.x;
  int a0 = (2 * t < nbuk) ? colsum[2 * t] : 0;
  int a1 = (2 * t + 1 < nbuk) ? colsum[2 * t + 1] : 0;
  int ps = a0 + a1;
  s[t] = ps;
  __syncthreads();
  for (int off = 1; off < 1024; off <<= 1) {
    int u = (t >= off) ? s[t - off] : 0;
    __syncthreads();
    s[t] += u;
    __syncthreads();
  }
  int excl = s[t] - ps;
  if (2 * t < nbuk) bbase[2 * t] = excl;
  if (2 * t + 1 < nbuk) bbase[2 * t + 1] = excl + a0;
  if (t == 0) bbase[nbuk] = total;
}

__global__ void offs_kernel(const int* __restrict__ hist, const int* __restrict__ bbase,
                            int* __restrict__ offs, int nbuk) {
  int b = blockIdx.x, t = threadIdx.x;  // 64 threads, one wave
  int v = hist[t * nbuk + b];
  int sum = v;
  for (int o = 1; o < 64; o <<= 1) {
    int u = __shfl_up(sum, o);
    if (t >= o) sum += u;
  }
  offs[t * nbuk + b] = bbase[b] + (sum - v);
}

__global__ __launch_bounds__(1024) void partition_kernel(
    const int* __restrict__ s1, const int* __restrict__ d1,
    const int* __restrict__ s2, const int* __restrict__ d2,
    const int* __restrict__ offs, int* __restrict__ ebuf,
    int ne, int off, int nbuk) {
  __shared__ int cur[MAXBUK];
  for (int i = threadIdx.x; i < nbuk; i += 1024)
    cur[i] = offs[blockIdx.x * nbuk + i];
  __syncthreads();
  int total = 2 * ne;
  int chunk = (total + gridDim.x - 1) / gridDim.x;
  int a = blockIdx.x * chunk;
  int b = min(total, a + chunk);
  for (int e = a + threadIdx.x; e < b; e += 1024) {
    int s, d;
    if (e < ne) { s = s1[e]; d = d1[e]; }
    else { s = s2[e - ne] + off; d = d2[e - ne] + off; }
    int p = atomicAdd(&cur[d >> 7], 1);
    ebuf[p] = (s << 7) | (d & 127);  // s < 2^18 -> fits 25 bits
  }
}

// counting-sort bucket edges by dst in LDS; also builds rowptr + dinv locally
__global__ __launch_bounds__(256) void bucket_sort_kernel(
    int* __restrict__ ebuf, const int* __restrict__ bbase,
    int* __restrict__ rowptr, float* __restrict__ dinv, int ntot, int nbuk) {
  __shared__ int buf[SCAP];
  __shared__ int outv[SCAP];
  __shared__ int h[128];
  __shared__ int sc[128];
  __shared__ int cur[128];
  int b = blockIdx.x, t = threadIdx.x;
  int v0 = b * 128;
  int e0 = bbase[b], e1 = bbase[b + 1];
  int cnt = e1 - e0;
  if (t < 128) h[t] = 0;
  for (int i = t; i < cnt; i += 256) buf[i] = ebuf[e0 + i];
  __syncthreads();
  for (int i = t; i < cnt; i += 256) atomicAdd(&h[buf[i] & 127], 1);
  __syncthreads();
  if (t < 128) sc[t] = h[t];
  __syncthreads();
  for (int off = 1; off < 128; off <<= 1) {
    int u = (t < 128 && t >= off) ? sc[t - off] : 0;
    __syncthreads();
    if (t < 128) sc[t] += u;
    __syncthreads();
  }
  if (t < 128) {
    int excl = sc[t] - h[t];
    cur[t] = excl;
    int v = v0 + t;
    if (v < ntot) {
      rowptr[v] = e0 + excl;
      dinv[v] = rsqrtf((float)(h[t] + 1));
    }
  }
  if (b == nbuk - 1 && t == 0) rowptr[ntot] = bbase[nbuk];
  __syncthreads();
  for (int i = t; i < cnt; i += 256) {
    int p = buf[i];
    int pos = atomicAdd(&cur[p & 127], 1);
    outv[pos] = p >> 7;
  }
  __syncthreads();
  for (int i = t; i < cnt; i += 256) ebuf[e0 + i] = outv[i];
}

// xh[v] = bf16(dinv[v] * x[v]), packed 4 bf16 per lane (uint2)
__global__ void xh_kernel(const float* __restrict__ x1, const float* __restrict__ x2,
                          const float* __restrict__ dinv, uint2* __restrict__ xh,
                          int n1, int ntot) {
  int tid = blockIdx.x * blockDim.x + threadIdx.x;
  int v = tid >> 5, l = tid & 31;
  if (v >= ntot) return;
  const float4* xr = (v < n1) ? (const float4*)(x1 + (size_t)v * 128)
                              : (const float4*)(x2 + (size_t)(v - n1) * 128);
  float4 xv = xr[l];
  float dv = dinv[v];
  unsigned b0 = bf16rne(dv * xv.x), b1 = bf16rne(dv * xv.y);
  unsigned b2 = bf16rne(dv * xv.z), b3 = bf16rne(dv * xv.w);
  uint2 w;
  w.x = (b1 << 16) | b0;
  w.y = (b3 << 16) | b2;
  xh[(size_t)v * 32 + l] = w;
}

// agg16[v] = bf16( dinv[v] * (xh[v] + sum_{s in N(v)} xh[s]) )
// 16 lanes per node, uint4 (8 bf16) per lane; 4-deep unrolled gather.
__global__ __launch_bounds__(256) void gather_kernel(
    const uint4* __restrict__ xh, const int* __restrict__ csr,
    const int* __restrict__ rowptr, const float* __restrict__ dinv,
    uv4* __restrict__ agg16, int ntot) {
  int tid = blockIdx.x * blockDim.x + threadIdx.x;
  int v = tid >> 4, l = tid & 15;
  if (v >= ntot) return;
  float4 a0, a1, b0, b1, c0, c1, d0, d1;
  bfunpack8(xh[(size_t)v * 16 + l], a0, a1);  // self term (pre-scaled by dinv[v])
  b0 = make_float4(0.f, 0.f, 0.f, 0.f); b1 = b0;
  c0 = b0; c1 = b0; d0 = b0; d1 = b0;
  int rs = __builtin_nontemporal_load(&rowptr[v]);
  int re = __builtin_nontemporal_load(&rowptr[v + 1]);
  int base = rs;
  for (; base + 16 <= re; base += 16) {
    int sown = __builtin_nontemporal_load(&csr[base + l]);
#pragma unroll
    for (int j = 0; j < 16; j += 4) {
      int s0 = __shfl(sown, j, 16);
      int s1 = __shfl(sown, j + 1, 16);
      int s2 = __shfl(sown, j + 2, 16);
      int s3 = __shfl(sown, j + 3, 16);
      uint4 w0 = xh[(size_t)s0 * 16 + l];
      uint4 w1 = xh[(size_t)s1 * 16 + l];
      uint4 w2 = xh[(size_t)s2 * 16 + l];
      uint4 w3 = xh[(size_t)s3 * 16 + l];
      float4 lo, hi;
      bfunpack8(w0, lo, hi); add8(a0, a1, lo, hi);
      bfunpack8(w1, lo, hi); add8(b0, b1, lo, hi);
      bfunpack8(w2, lo, hi); add8(c0, c1, lo, hi);
      bfunpack8(w3, lo, hi); add8(d0, d1, lo, hi);
    }
  }
  if (base < re) {
    int idx = base + l;
    int sown = (idx < re) ? __builtin_nontemporal_load(&csr[idx]) : 0;
    int m = re - base;
    for (int j = 0; j < m; j++) {
      int s = __shfl(sown, j, 16);
      float4 lo, hi;
      bfunpack8(xh[(size_t)s * 16 + l], lo, hi);
      add8(a0, a1, lo, hi);
    }
  }
  add8(a0, a1, b0, b1);
  add8(c0, c1, d0, d1);
  add8(a0, a1, c0, c1);
  float dv = dinv[v];
  uv4 w;
  w.x = (bf16rne(dv * a0.y) << 16) | bf16rne(dv * a0.x);
  w.y = (bf16rne(dv * a0.w) << 16) | bf16rne(dv * a0.z);
  w.z = (bf16rne(dv * a1.y) << 16) | bf16rne(dv * a1.x);
  w.w = (bf16rne(dv * a1.w) << 16) | bf16rne(dv * a1.z);
  __builtin_nontemporal_store(w, &agg16[(size_t)v * 16 + l]);
}

// W (fp32 [k][n]) -> Wt (bf16 [n][k]) for both convs
__global__ void wconv_kernel(const float* __restrict__ W1, const float* __restrict__ W2,
                             unsigned short* __restrict__ Wt1,
                             unsigned short* __restrict__ Wt2) {
  int idx = blockIdx.x * 256 + threadIdx.x;  // 0..16383
  int k = idx >> 7, n = idx & 127;
  Wt1[n * 128 + k] = (unsigned short)bf16rne(W1[idx]);
  Wt2[n * 128 + k] = (unsigned short)bf16rne(W2[idx]);
}

// ---------- MFMA GEMM (bf16 A x bf16 W^T) + lrelu + segment-max epilogue ----------
// 128x128 tile/block, 4 waves; A frags loaded straight from row-major agg16,
// B frags from pre-transposed Wt — both already in native mfma operand layout.
__global__ __launch_bounds__(256) void gemm_mfma_pool_kernel(
    const bf16x8* __restrict__ A8,      // agg16: row r frag q at [r*16 + q]
    const bf16x8* __restrict__ Wt1, const float* __restrict__ b1,
    const bf16x8* __restrict__ Wt2, const float* __restrict__ b2,
    const int* __restrict__ batch1, const int* __restrict__ batch2,
    unsigned* __restrict__ gbuf, int N1, int Ntot, int nbA) {
  __shared__ int sgid[128];
  __shared__ unsigned lmax[8 * 128];
  __shared__ int s_span;
  int b = blockIdx.x;
  int half = (b >= nbA) ? 1 : 0;
  const bf16x8* Wt = half ? Wt2 : Wt1;
  const float* bias = half ? b2 : b1;
  int base = half ? (N1 + (b - nbA) * GTILE) : b * GTILE;
  int rmax = half ? Ntot : N1;
  int t = threadIdx.x;
  int w = t >> 6, lane = t & 63;
  int quad = lane >> 4, lr = lane & 15;

  if (t < 128) {
    int gr = base + t;
    int gid = -1;
    if (gr < rmax) gid = half ? (BGRAPH + batch2[gr - N1]) : batch1[gr];
    sgid[t] = gid;
  }
  for (int i = t; i < 8 * 128; i += 256) lmax[i] = 0u;
  __syncthreads();
  int g0 = sgid[0];
  if (t == 0) {
    int mg = g0;
    for (int r = 127; r >= 0; r--) {
      if (sgid[r] >= 0) { mg = sgid[r]; break; }
    }
    s_span = mg - g0 + 1;
  }

  f32x4 acc[2][8];
#pragma unroll
  for (int si = 0; si < 2; si++)
#pragma unroll
    for (int ct = 0; ct < 8; ct++) acc[si][ct] = (f32x4){0.f, 0.f, 0.f, 0.f};

  int r0 = base + w * 16 + lr;        // slab w
  int r1 = base + (w + 4) * 16 + lr;  // slab w+4
#pragma unroll
  for (int kq = 0; kq < 4; kq++) {
    bf16x8 a0 = {0, 0, 0, 0, 0, 0, 0, 0};
    bf16x8 a1 = {0, 0, 0, 0, 0, 0, 0, 0};
    if (r0 < rmax) a0 = A8[(size_t)r0 * 16 + kq * 4 + quad];
    if (r1 < rmax) a1 = A8[(size_t)r1 * 16 + kq * 4 + quad];
#pragma unroll
    for (int ct = 0; ct < 8; ct++) {
      bf16x8 bf = Wt[(size_t)(ct * 16 + lr) * 16 + kq * 4 + quad];
      acc[0][ct] = __builtin_amdgcn_mfma_f32_16x16x32_bf16(a0, bf, acc[0][ct], 0, 0, 0);
      acc[1][ct] = __builtin_amdgcn_mfma_f32_16x16x32_bf16(a1, bf, acc[1][ct], 0, 0, 0);
    }
  }

  float bv[8];
#pragma unroll
  for (int ct = 0; ct < 8; ct++) bv[ct] = bias[ct * 16 + lr];
#pragma unroll
  for (int si = 0; si < 2; si++) {
    int slab = (si == 0) ? w : (w + 4);
#pragma unroll
    for (int reg = 0; reg < 4; reg++) {
      int rl = slab * 16 + quad * 4 + reg;  // C/D: row = quad*4+reg, col = lr
      int gid = sgid[rl];
      if (gid < 0) continue;
      int loc = gid - g0;
#pragma unroll
      for (int ct = 0; ct < 8; ct++) {
        unsigned key = fkey(lrelu(acc[si][ct][reg] + bv[ct]));
        if (loc < 8) atomicMax(&lmax[loc * 128 + ct * 16 + lr], key);
        else atomicMax(&gbuf[(size_t)gid * 128 + ct * 16 + lr], key);
      }
    }
  }
  __syncthreads();
  int span = s_span; if (span > 8) span = 8;
  for (int i = t; i < span * 128; i += 256) {
    unsigned k = lmax[i];
    if (k) atomicMax(&gbuf[(size_t)(g0 + (i >> 7)) * 128 + (i & 127)], k);
  }
}

__global__ void ginit_kernel(unsigned* __restrict__ gbuf, int n) {
  int i = blockIdx.x * blockDim.x + threadIdx.x;
  if (i < n) gbuf[i] = 0u;
}

// ---------- fused head (decodes pooled g) ----------

__global__ __launch_bounds__(256) void head_kernel(
    const unsigned* __restrict__ gbuf,
    const float* __restrict__ fcp1W, const float* __restrict__ fcp1b,
    const float* __restrict__ fcp2W, const float* __restrict__ fcp2b,
    const float* __restrict__ fc1W, const float* __restrict__ fc1b,
    const float* __restrict__ fc2W, const float* __restrict__ fc2b,
    const float* __restrict__ outW, const float* __restrict__ outb,
    float* __restrict__ out) {
  __shared__ float grow[256];
  __shared__ float c[256];
  __shared__ float h1[256];
  __shared__ float h2[64];
  int b = blockIdx.x, t = threadIdx.x;
  grow[t] = (t < 128) ? fdec(gbuf[(size_t)b * 128 + t])
                      : fdec(gbuf[(size_t)(BGRAPH + b) * 128 + (t - 128)]);
  __syncthreads();
  {
    float acc;
    if (t < 128) {
      acc = fcp1b[t];
      for (int k = 0; k < 128; k++) acc = fmaf(grow[k], fcp1W[k * 128 + t], acc);
    } else {
      int tc = t - 128;
      acc = fcp2b[tc];
      for (int k = 0; k < 128; k++) acc = fmaf(grow[128 + k], fcp2W[k * 128 + tc], acc);
    }
    c[t] = lrelu(acc);
  }
  __syncthreads();
  {
    float acc = fc1b[t];
    for (int k = 0; k < 256; k++) acc = fmaf(c[k], fc1W[k * 256 + t], acc);
    h1[t] = lrelu(acc);
  }
  __syncthreads();
  if (t < 64) {
    float acc = fc2b[t];
    for (int k = 0; k < 256; k++) acc = fmaf(h1[k], fc2W[k * 64 + t], acc);
    h2[t] = lrelu(acc);
  }
  __syncthreads();
  if (t < 64) {
    float v = h2[t] * outW[t];
    for (int off = 32; off > 0; off >>= 1) v += __shfl_down(v, off);
    if (t == 0) out[b] = 1.f / (1.f + expf(-(v + outb[0])));
  }
}

extern "C" void kernel_launch(void* const* d_in, const int* in_sizes, int n_in,
                              void* d_out, int out_size, void* d_ws, size_t ws_size,
                              hipStream_t stream) {
  const float* x1 = (const float*)d_in[0];
  const float* x2 = (const float*)d_in[1];
  const int* ei1 = (const int*)d_in[2];
  const int* ei2 = (const int*)d_in[3];
  const int* batch1 = (const int*)d_in[4];
  const int* batch2 = (const int*)d_in[5];
  const float* conv1W = (const float*)d_in[6];
  const float* conv1b = (const float*)d_in[7];
  const float* conv2W = (const float*)d_in[8];
  const float* conv2b = (const float*)d_in[9];
  const float* fcp1W = (const float*)d_in[10];
  const float* fcp1b = (const float*)d_in[11];
  const float* fcp2W = (const float*)d_in[12];
  const float* fcp2b = (const float*)d_in[13];
  const float* fc1W = (const float*)d_in[14];
  const float* fc1b = (const float*)d_in[15];
  const float* fc2W = (const float*)d_in[16];
  const float* fc2b = (const float*)d_in[17];
  const float* outW = (const float*)d_in[18];
  const float* outb = (const float*)d_in[19];

  int N = in_sizes[0] / 128;
  int E = in_sizes[2] / 2;
  int NT = 2 * N;
  int NBUK = (NT + 127) / 128;

  char* ws = (char*)d_ws;
  size_t off = 0;
  auto alloc = [&](size_t bytes) -> void* {
    void* p = ws + off;
    off += (bytes + 511) & ~(size_t)511;
    return p;
  };
  uint2* xh = (uint2*)alloc((size_t)NT * 256);         // 51.2 MB bf16 features
  uint2* agg16 = (uint2*)alloc((size_t)NT * 256);      // 51.2 MB bf16 agg
  int* ebuf = (int*)alloc((size_t)2 * E * 4);          // 12.8 MB
  int* rowptr = (int*)alloc((size_t)(NT + 1) * 4);
  float* dinv = (float*)alloc((size_t)NT * 4);
  int* hist = (int*)alloc((size_t)PNB * NBUK * 4);
  int* offs = (int*)alloc((size_t)PNB * NBUK * 4);
  int* colsum = (int*)alloc((size_t)NBUK * 4);
  int* bbase = (int*)alloc((size_t)(NBUK + 1) * 4);
  unsigned* gbuf = (unsigned*)alloc((size_t)2 * BGRAPH * 128 * 4);
  unsigned short* Wt1 = (unsigned short*)alloc((size_t)128 * 128 * 2);
  unsigned short* Wt2 = (unsigned short*)alloc((size_t)128 * 128 * 2);
  (void)ws_size; (void)n_in; (void)out_size;

  const int* src1 = ei1, *dst1 = ei1 + E;
  const int* src2 = ei2, *dst2 = ei2 + E;

  hist_kernel<<<PNB, 1024, 0, stream>>>(dst1, dst2, hist, E, N, NBUK);
  colsum_kernel<<<NBUK, 64, 0, stream>>>(hist, colsum, NBUK);
  bscan_kernel<<<1, 1024, 0, stream>>>(colsum, bbase, NBUK, 2 * E);
  offs_kernel<<<NBUK, 64, 0, stream>>>(hist, bbase, offs, NBUK);
  partition_kernel<<<PNB, 1024, 0, stream>>>(src1, dst1, src2, dst2, offs, ebuf, E, N, NBUK);
  bucket_sort_kernel<<<NBUK, 256, 0, stream>>>(ebuf, bbase, rowptr, dinv, NT, NBUK);
  xh_kernel<<<(unsigned)(((size_t)NT * 32 + 255) / 256), 256, 0, stream>>>(
      x1, x2, dinv, xh, N, NT);
  gather_kernel<<<(unsigned)(((size_t)NT * 16 + 255) / 256), 256, 0, stream>>>(
      (const uint4*)xh, ebuf, rowptr, dinv, (uv4*)agg16, NT);
  wconv_kernel<<<64, 256, 0, stream>>>(conv1W, conv2W, Wt1, Wt2);
  ginit_kernel<<<(2 * BGRAPH * 128 + 255) / 256, 256, 0, stream>>>(gbuf, 2 * BGRAPH * 128);
  int nbA = (N + GTILE - 1) / GTILE;
  gemm_mfma_pool_kernel<<<2 * nbA, 256, 0, stream>>>(
      (const bf16x8*)agg16, (const bf16x8*)Wt1, conv1b, (const bf16x8*)Wt2, conv2b,
      batch1, batch2, gbuf, N, NT, nbA);
  head_kernel<<<BGRAPH, 256, 0, stream>>>(gbuf, fcp1W, fcp1b, fcp2W, fcp2b,
                                          fc1W, fc1b, fc2W, fc2b, outW, outb,
                                          (float*)d_out);
}